// Round 11
// baseline (2152.207 us; speedup 1.0000x reference)
//
#include <hip/hip_runtime.h>
#include <math.h>

// NeuroSAT, MI355X. Round 11: LDS-issue-bound gemm fixed by row-pairing.
//  - r3-r10 all plateaued ~72us/step: gemm16 issues 17 ds_read_b128 per 64
//    FMA (16 weight-broadcast + 1 row) = ~204 LDS cy vs 128 VALU cy ->
//    LDS-bound 1.6x (VALUBusy stuck at 28% for 7 rounds).
//  - Now each thread computes 2 ROWS x 16 outputs: one weight read feeds 8
//    FMAs -> 18 LDS / 256 VALU cy per k4 = VALU-bound. Pair-interleaving
//    makes flip(2l)=2l+1 the same thread's other row. Each weight matrix
//    keeps its own k-ascending loop into the same acc -> BIT-IDENTICAL
//    numerics (absmax must be exactly 0.01367188).
//  - Setup kernels parallelized (one output per thread): ~250us -> ~40us.
//  - Structure: 2 dispatches/step (r10), blocks 512 thr / 8 waves.

#define NV2_   800
#define NC_    440
#define KK_    12
#define NPG_   1240
#define NLIT_  12800
#define NCLS_  7040
#define NE_    84480
#define NN_    19840
#define STEPS_ 23

__device__ __forceinline__ float sigmf(float x) { return 1.0f / (1.0f + __expf(-x)); }
__device__ __forceinline__ float tanhf_(float x) { return 1.0f - 2.0f / (__expf(2.0f * x) + 1.0f); }

// ---------------- setup kernels (parallelized, same summation order) ----------------

// T = w1@w2 per MLP; ub = b1@w2 + b2. grid 128 (mlp r = blk>>6, row i = blk&63) x 64 thr.
__global__ __launch_bounds__(64) void collapseT_k(
    const float* lm1, const float* lm1b, const float* lm2, const float* lm2b,
    const float* cm1, const float* cm1b, const float* cm2, const float* cm2b,
    float* T, float* ub)
{
    int r = blockIdx.x >> 6, i = blockIdx.x & 63, j = threadIdx.x;
    const float* w1 = r ? cm1 : lm1; const float* b1 = r ? cm1b : lm1b;
    const float* w2 = r ? cm2 : lm2; const float* b2 = r ? cm2b : lm2b;
    float s = 0.f;
    for (int k = 0; k < 64; ++k) s += w1[i * 64 + k] * w2[k * 64 + j];
    T[r * 4096 + i * 64 + j] = s;
    if (i == 0) {
        float s2 = 0.f;
        for (int k = 0; k < 64; ++k) s2 += b1[k] * w2[k * 64 + j];
        ub[r * 64 + j] = s2 + b2[j];
    }
}

// W = T@w3; bb = ub@w3 + b3.
__global__ __launch_bounds__(64) void collapseW_k(
    const float* lm3, const float* lm3b, const float* cm3, const float* cm3b,
    const float* T, const float* ub,
    float* Wl, float* bl, float* Wc, float* bc)
{
    int r = blockIdx.x >> 6, i = blockIdx.x & 63, j = threadIdx.x;
    const float* w3 = r ? cm3 : lm3; const float* b3 = r ? cm3b : lm3b;
    float* W = r ? Wc : Wl; float* bb = r ? bc : bl;
    float s = 0.f;
    for (int k = 0; k < 64; ++k) s += T[r * 4096 + i * 64 + k] * w3[k * 64 + j];
    W[i * 64 + j] = s;
    if (i == 0) {
        float s2 = 0.f;
        for (int k = 0; k < 64; ++k) s2 += ub[r * 64 + k] * w3[k * 64 + j];
        bb[j] = s2 + b3[j];
    }
}

__global__ __launch_bounds__(64) void votecol_k(
    const float* lv1, const float* lv1b, const float* lv2, const float* lv2b,
    const float* lv3, const float* lv3b, float* Wv, float* bv)
{
    __shared__ float t3[64];
    __shared__ float ub2[64];
    int t = threadIdx.x;
    float s = 0.f;
    for (int j = 0; j < 64; ++j) s += lv2[t * 64 + j] * lv3[j];
    t3[t] = s;
    float s2 = 0.f;
    for (int k = 0; k < 64; ++k) s2 += lv1b[k] * lv2[k * 64 + t];
    ub2[t] = s2 + lv2b[t];
    __syncthreads();
    float s3 = 0.f;
    for (int k = 0; k < 64; ++k) s3 += lv1[t * 64 + k] * t3[k];
    Wv[t] = s3;
    if (t == 0) {
        float v = 0.f;
        for (int j = 0; j < 64; ++j) v += ub2[j] * lv3[j];
        bv[0] = v + lv3b[0];
    }
}

// fold: grid 128 (target t = blk>>6, row i = blk&63) x 256 thr j.
__global__ __launch_bounds__(256) void fold2_k(
    const float* Wl, const float* bl, const float* Wc, const float* bc,
    const float* lwih, const float* lbih, const float* lbhh,
    const float* cwih, const float* cbih, const float* cbhh,
    float* Wfl, float* bfl, float* Bl, float* Wfc, float* Bc)
{
    int t = blockIdx.x >> 6, i = blockIdx.x & 63, j = threadIdx.x;
    if (t == 0) {
        float s = 0.f;
        for (int m = 0; m < 64; ++m) s += Wc[i * 64 + m] * lwih[(64 + m) * 256 + j];
        Wfl[i * 256 + j] = s;
        if (i == 0) {
            float s2 = 0.f;
            for (int m = 0; m < 64; ++m) s2 += bc[m] * lwih[(64 + m) * 256 + j];
            bfl[j] = s2;
            Bl[j] = lbih[j] + lbhh[j];
        }
    } else {
        float s = 0.f;
        for (int m = 0; m < 64; ++m) s += Wl[i * 64 + m] * cwih[m * 256 + j];
        Wfc[i * 256 + j] = s;
        if (i == 0) {
            float s2 = 0.f;
            for (int m = 0; m < 64; ++m) s2 += bl[m] * cwih[m * 256 + j];
            Bc[j] = cbih[j] + cbhh[j] + 13.f * s2;
        }
    }
}

__global__ __launch_bounds__(256) void init_k(
    const float* x, const float* liw, const float* lib, const float* ciw, const float* cib,
    float* out0, float* outc)
{
    int t = blockIdx.x * 256 + threadIdx.x;
    if (t >= NN_ * 64) return;
    int node = t >> 6, j = t & 63;
    int b = node / NPG_;
    int i = node - b * NPG_;
    float x0 = x[node * 2 + 0], x1 = x[node * 2 + 1];
    if (i < NV2_) {
        int sp = (i < 400) ? 2 * i : 2 * (i - 400) + 1;
        out0[(size_t)(b * NV2_ + sp) * 64 + j] = x0 * liw[j] + x1 * liw[64 + j] + lib[j];
    } else {
        outc[(size_t)(b * NC_ + (i - NV2_)) * 64 + j] = x0 * ciw[j] + x1 * ciw[64 + j] + cib[j];
    }
}

__global__ __launch_bounds__(256) void econv_k(const int* ei, int* llits, int* cnt)
{
    int e = blockIdx.x * 256 + threadIdx.x;
    if (e >= NE_) return;
    int g = ei[e];
    int b = g / NPG_;
    int i = g - b * NPG_;
    int sp = (i < 400) ? 2 * i : 2 * (i - 400) + 1;
    int L = b * NV2_ + sp;
    llits[e] = L;
    atomicAdd(cnt + L, 1);
}

__global__ __launch_bounds__(1024) void scan_k(const int* cnt, int* rowptr, int* cursor)
{
    __shared__ int sums[1024];
    int t = threadIdx.x;
    int i0 = t * 13;
    int i1 = i0 + 13; if (i1 > NLIT_) i1 = NLIT_; if (i0 > NLIT_) i0 = NLIT_;
    int s = 0;
    for (int i = i0; i < i1; ++i) s += cnt[i];
    sums[t] = s;
    __syncthreads();
    for (int off = 1; off < 1024; off <<= 1) {
        int v = (t >= off) ? sums[t - off] : 0;
        __syncthreads();
        sums[t] += v;
        __syncthreads();
    }
    int run = sums[t] - s;
    for (int i = i0; i < i1; ++i) { rowptr[i] = run; cursor[i] = run; run += cnt[i]; }
    if (t == 1023) rowptr[NLIT_] = sums[1023];
}

__global__ __launch_bounds__(256) void fill_k(const int* llits, int* cursor, int* col)
{
    int e = blockIdx.x * 256 + threadIdx.x;
    if (e >= NE_) return;
    int pos = atomicAdd(cursor + llits[e], 1);
    col[pos] = e / KK_;
}

// ---------------- paired gemm: a0 += in0@W, a1 += in1@W (shared weight reads) ----------------

template<int WC, int GS>
__device__ __forceinline__ void gemm16p(const float* __restrict__ in0,
                                        const float* __restrict__ in1,
                                        const float* __restrict__ W,
                                        int uc4, float* a0, float* a1)
{
    const float4* p0 = (const float4*)in0;
    const float4* p1 = (const float4*)in1;
#pragma unroll 4
    for (int k4 = 0; k4 < 16; ++k4) {
        float4 v0 = p0[k4], v1 = p1[k4];
        const float* wk = W + (k4 * 4) * WC + uc4;
#pragma unroll
        for (int e = 0; e < 4; ++e) {
            float u0 = (e == 0) ? v0.x : (e == 1) ? v0.y : (e == 2) ? v0.z : v0.w;
            float u1 = (e == 0) ? v1.x : (e == 1) ? v1.y : (e == 2) ? v1.z : v1.w;
            const float* wb = wk + e * WC;
#pragma unroll
            for (int g = 0; g < 4; ++g) {
                float4 w = *(const float4*)(wb + g * GS);
                a0[g * 4 + 0] = fmaf(u0, w.x, a0[g * 4 + 0]);
                a0[g * 4 + 1] = fmaf(u0, w.y, a0[g * 4 + 1]);
                a0[g * 4 + 2] = fmaf(u0, w.z, a0[g * 4 + 2]);
                a0[g * 4 + 3] = fmaf(u0, w.w, a0[g * 4 + 3]);
                a1[g * 4 + 0] = fmaf(u1, w.x, a1[g * 4 + 0]);
                a1[g * 4 + 1] = fmaf(u1, w.y, a1[g * 4 + 1]);
                a1[g * 4 + 2] = fmaf(u1, w.z, a1[g * 4 + 2]);
                a1[g * 4 + 3] = fmaf(u1, w.w, a1[g * 4 + 3]);
            }
        }
    }
}

__device__ __forceinline__ void cell4(const float* acc, float* c, float* h)
{
#pragma unroll
    for (int q = 0; q < 4; ++q) {
        float iv = sigmf(acc[q]);
        float fv = sigmf(acc[4 + q]);
        float gv = tanhf_(acc[8 + q]);
        float ov = sigmf(acc[12 + q]);
        float c2 = fv * c[q] + iv * gv;
        c[q] = c2;
        h[q] = ov * tanhf_(c2);
    }
}

// ---------------- per-step kernels (512 thr, 8 waves, 2 rows/thread) ----------------

__global__ __launch_bounds__(512) void clause_step_k(
    const float* __restrict__ out_cur, const float* __restrict__ outc0,
    float* __restrict__ ch_cur, const float* __restrict__ ch_prev, float* __restrict__ ccg,
    const int* __restrict__ llits,
    const float* __restrict__ Wfc, const float* __restrict__ cwhh, const float* __restrict__ Bc,
    int step)
{
    __shared__ float wfc_s[8192];
    __shared__ float cwhh_s[8192];
    __shared__ float LM[128 * 68];
    __shared__ float CH[128 * 68];
    const int tid = threadIdx.x;
    const int lane = tid & 63;
    const int wv = tid >> 6;               // 0..7 = unit group
    const int rowgrp = blockIdx.x >> 1;
    const int half = blockIdx.x & 1;
    const int U0 = half * 32;
    const int Cb = rowgrp * 128;

    for (int i2 = tid; i2 < 8192; i2 += 512) {
        int k = i2 >> 7, r = i2 & 127, gg = r >> 5, j = r & 31;
        int src = k * 256 + gg * 64 + U0 + j;
        wfc_s[i2]  = Wfc[src];
        cwhh_s[i2] = cwhh[src];
    }

    // gather: 8 waves x 16 rows, lane = column
    for (int s16 = 0; s16 < 16; ++s16) {
        int srow = wv * 16 + s16;
        int c = Cb + srow;
        float v;
        if (step) {
            float ch0 = ch_prev[(size_t)c * 64 + lane];
            CH[srow * 68 + lane] = ch0;
            v = ch0;
        } else {
            v = outc0[(size_t)c * 64 + lane];
        }
        const int* lp = llits + c * KK_;
        float t0 = out_cur[(size_t)lp[0] * 64 + lane];
        float t1 = out_cur[(size_t)lp[1] * 64 + lane];
        float t2 = out_cur[(size_t)lp[2] * 64 + lane];
        float t3 = out_cur[(size_t)lp[3] * 64 + lane];
        float t4 = out_cur[(size_t)lp[4] * 64 + lane];
        float t5 = out_cur[(size_t)lp[5] * 64 + lane];
        float t6 = out_cur[(size_t)lp[6] * 64 + lane];
        float t7 = out_cur[(size_t)lp[7] * 64 + lane];
        float t8 = out_cur[(size_t)lp[8] * 64 + lane];
        float t9 = out_cur[(size_t)lp[9] * 64 + lane];
        float ta = out_cur[(size_t)lp[10] * 64 + lane];
        float tb = out_cur[(size_t)lp[11] * 64 + lane];
        v += t0 + t1 + t2 + t3 + t4 + t5 + t6 + t7 + t8 + t9 + ta + tb;
        LM[srow * 68 + lane] = v;
    }
    __syncthreads();

    const int uc4 = wv * 4;
    const int r0 = 2 * lane, r1 = 2 * lane + 1;
    const int c0_ = Cb + r0, c1_ = Cb + r1;
    const int unit0 = U0 + uc4;

    float acc0[16], acc1[16];
    if (step) {
        float w0[16], w1[16];
#pragma unroll
        for (int i = 0; i < 16; ++i) { w0[i] = 0.f; w1[i] = 0.f; }
        gemm16p<128, 32>(CH + (size_t)r0 * 68, CH + (size_t)r1 * 68, cwhh_s, uc4, w0, w1);
#pragma unroll
        for (int g = 0; g < 4; ++g)
#pragma unroll
            for (int q = 0; q < 4; ++q) {
                float b = Bc[g * 64 + unit0 + q];
                acc0[g * 4 + q] = b + w0[g * 4 + q];
                acc1[g * 4 + q] = b + w1[g * 4 + q];
            }
    } else {
#pragma unroll
        for (int g = 0; g < 4; ++g)
#pragma unroll
            for (int q = 0; q < 4; ++q) {
                float b = Bc[g * 64 + unit0 + q];
                acc0[g * 4 + q] = b;
                acc1[g * 4 + q] = b;
            }
    }
    gemm16p<128, 32>(LM + (size_t)r0 * 68, LM + (size_t)r1 * 68, wfc_s, uc4, acc0, acc1);

    float cc0[4], cc1[4];
    if (step) {
        float4 p0 = *(const float4*)(ccg + (size_t)c0_ * 64 + unit0);
        float4 p1 = *(const float4*)(ccg + (size_t)c1_ * 64 + unit0);
        cc0[0] = p0.x; cc0[1] = p0.y; cc0[2] = p0.z; cc0[3] = p0.w;
        cc1[0] = p1.x; cc1[1] = p1.y; cc1[2] = p1.z; cc1[3] = p1.w;
    } else {
#pragma unroll
        for (int q = 0; q < 4; ++q) { cc0[q] = 0.f; cc1[q] = 0.f; }
    }
    float h0[4], h1[4];
    cell4(acc0, cc0, h0);
    cell4(acc1, cc1, h1);
    *(float4*)(ch_cur + (size_t)c0_ * 64 + unit0) = make_float4(h0[0], h0[1], h0[2], h0[3]);
    *(float4*)(ch_cur + (size_t)c1_ * 64 + unit0) = make_float4(h1[0], h1[1], h1[2], h1[3]);
    *(float4*)(ccg + (size_t)c0_ * 64 + unit0) = make_float4(cc0[0], cc0[1], cc0[2], cc0[3]);
    *(float4*)(ccg + (size_t)c1_ * 64 + unit0) = make_float4(cc1[0], cc1[1], cc1[2], cc1[3]);
}

__global__ __launch_bounds__(512) void lit_step_k(
    const float* __restrict__ out_cur, float* __restrict__ out_nxt,
    const float* __restrict__ chg, float* __restrict__ lcg,
    const int* __restrict__ rowptr, const int* __restrict__ col,
    const float* __restrict__ lwih, const float* __restrict__ lwhh, const float* __restrict__ Wfl,
    const float* __restrict__ bfl, const float* __restrict__ Bl,
    const float* __restrict__ Wv, const float* __restrict__ bv, float* __restrict__ vout,
    int step)
{
    __shared__ float wih_s[8192];
    __shared__ float whh_s[8192];
    __shared__ float wfl_s[8192];
    __shared__ float buf[128 * 68];
    const int tid = threadIdx.x;
    const int lane = tid & 63;
    const int wv = tid >> 6;               // 0..7 = unit group
    const int rowgrp = blockIdx.x >> 1;
    const int half = blockIdx.x & 1;
    const int U0 = half * 32;
    const int Lb = rowgrp * 128;

    for (int i2 = tid; i2 < 8192; i2 += 512) {
        int k = i2 >> 7, r = i2 & 127, gg = r >> 5, j = r & 31;
        int src = k * 256 + gg * 64 + U0 + j;
        wih_s[i2] = lwih[src];
        whh_s[i2] = lwhh[src];
        wfl_s[i2] = Wfl[src];
    }

    // load 128 out rows (coalesced float4, 4 passes)
    {
        const int trow = tid >> 4;
        const int tc4 = (tid & 15) << 2;
#pragma unroll
        for (int p = 0; p < 4; ++p)
            *(float4*)(buf + (trow + p * 32) * 68 + tc4) =
                *(const float4*)(out_cur + (size_t)(Lb + trow + p * 32) * 64 + tc4);
    }
    __syncthreads();

    const int uc4 = wv * 4;
    const int r0 = 2 * lane, r1 = 2 * lane + 1;
    const int R0 = Lb + r0, R1 = Lb + r1;
    const int unit0 = U0 + uc4;
    const float deg0 = 1.f + (float)(rowptr[R0 + 1] - rowptr[R0]);
    const float deg1 = 1.f + (float)(rowptr[R1 + 1] - rowptr[R1]);

    float acc0[16], acc1[16];
#pragma unroll
    for (int g = 0; g < 4; ++g)
#pragma unroll
        for (int q = 0; q < 4; ++q) {
            float b = Bl[g * 64 + unit0 + q];
            float f = bfl[g * 64 + unit0 + q];
            acc0[g * 4 + q] = b + deg0 * f;
            acc1[g * 4 + q] = b + deg1 * f;
        }

    // flip gemm: row r0's input is row r1 and vice versa (pair-interleave)
    gemm16p<128, 32>(buf + (size_t)r1 * 68, buf + (size_t)r0 * 68, wih_s, uc4, acc0, acc1);
    if (step)
        gemm16p<128, 32>(buf + (size_t)r0 * 68, buf + (size_t)r1 * 68, whh_s, uc4, acc0, acc1);
    __syncthreads();   // gemm reads of buf done before gather overwrites

    // CSR gather: 8 waves x 16 rows, lane = column
    for (int s16 = 0; s16 < 16; ++s16) {
        int srow = wv * 16 + s16;
        int l = Lb + srow;
        int e = rowptr[l], eE = rowptr[l + 1];
        float v = buf[srow * 68 + lane];
        for (; e + 8 <= eE; e += 8) {
            float t0 = chg[(size_t)col[e    ] * 64 + lane];
            float t1 = chg[(size_t)col[e + 1] * 64 + lane];
            float t2 = chg[(size_t)col[e + 2] * 64 + lane];
            float t3 = chg[(size_t)col[e + 3] * 64 + lane];
            float t4 = chg[(size_t)col[e + 4] * 64 + lane];
            float t5 = chg[(size_t)col[e + 5] * 64 + lane];
            float t6 = chg[(size_t)col[e + 6] * 64 + lane];
            float t7 = chg[(size_t)col[e + 7] * 64 + lane];
            v += ((t0 + t1) + (t2 + t3)) + ((t4 + t5) + (t6 + t7));
        }
        for (; e + 4 <= eE; e += 4) {
            float t0 = chg[(size_t)col[e    ] * 64 + lane];
            float t1 = chg[(size_t)col[e + 1] * 64 + lane];
            float t2 = chg[(size_t)col[e + 2] * 64 + lane];
            float t3 = chg[(size_t)col[e + 3] * 64 + lane];
            v += t0 + t1 + t2 + t3;
        }
        for (; e < eE; ++e) v += chg[(size_t)col[e] * 64 + lane];
        buf[srow * 68 + lane] = v;
    }
    __syncthreads();
    gemm16p<128, 32>(buf + (size_t)r0 * 68, buf + (size_t)r1 * 68, wfl_s, uc4, acc0, acc1);

    float lc0[4], lc1[4];
    if (step) {
        float4 p0 = *(const float4*)(lcg + (size_t)R0 * 64 + unit0);
        float4 p1 = *(const float4*)(lcg + (size_t)R1 * 64 + unit0);
        lc0[0] = p0.x; lc0[1] = p0.y; lc0[2] = p0.z; lc0[3] = p0.w;
        lc1[0] = p1.x; lc1[1] = p1.y; lc1[2] = p1.z; lc1[3] = p1.w;
    } else {
#pragma unroll
        for (int q = 0; q < 4; ++q) { lc0[q] = 0.f; lc1[q] = 0.f; }
    }
    float h0[4], h1[4];
    cell4(acc0, lc0, h0);
    cell4(acc1, lc1, h1);
    *(float4*)(out_nxt + (size_t)R0 * 64 + unit0) = make_float4(h0[0], h0[1], h0[2], h0[3]);
    *(float4*)(out_nxt + (size_t)R1 * 64 + unit0) = make_float4(h1[0], h1[1], h1[2], h1[3]);
    *(float4*)(lcg + (size_t)R0 * 64 + unit0) = make_float4(lc0[0], lc0[1], lc0[2], lc0[3]);
    *(float4*)(lcg + (size_t)R1 * 64 + unit0) = make_float4(lc1[0], lc1[1], lc1[2], lc1[3]);

    if (step == STEPS_ - 1) {
        float p0 = h0[0] * Wv[unit0] + h0[1] * Wv[unit0 + 1]
                 + h0[2] * Wv[unit0 + 2] + h0[3] * Wv[unit0 + 3];
        float p1 = h1[0] * Wv[unit0] + h1[1] * Wv[unit0 + 1]
                 + h1[2] * Wv[unit0 + 2] + h1[3] * Wv[unit0 + 3];
        __syncthreads();
        buf[r0 * 8 + wv] = p0;
        buf[r1 * 8 + wv] = p1;
        __syncthreads();
        if (wv == 0) {
#pragma unroll
            for (int rr = 0; rr < 2; ++rr) {
                int row = 2 * lane + rr;
                int R = Lb + row;
                float v = (half == 0) ? bv[0] : 0.f;
#pragma unroll
                for (int w = 0; w < 8; ++w) v += buf[row * 8 + w];
                int b = R / NV2_;
                int pos = R - b * NV2_;
                int pi = (pos >> 1) + (pos & 1) * 400;   // undo pair-interleave
                atomicAdd(vout + b * NPG_ + pi, v);
            }
        }
    }
}

// ---------------- host ----------------

extern "C" void kernel_launch(void* const* d_in, const int* in_sizes, int n_in,
                              void* d_out, int out_size, void* d_ws, size_t ws_size,
                              hipStream_t stream)
{
    (void)in_sizes; (void)n_in; (void)out_size; (void)ws_size;
    const float* x    = (const float*)d_in[0];
    const int*   ei   = (const int*)d_in[2];
    const float* liw  = (const float*)d_in[4];
    const float* lib  = (const float*)d_in[5];
    const float* ciw  = (const float*)d_in[6];
    const float* cib  = (const float*)d_in[7];
    const float* lm1  = (const float*)d_in[8];
    const float* lm1b = (const float*)d_in[9];
    const float* lm2  = (const float*)d_in[10];
    const float* lm2b = (const float*)d_in[11];
    const float* lm3  = (const float*)d_in[12];
    const float* lm3b = (const float*)d_in[13];
    const float* cm1  = (const float*)d_in[14];
    const float* cm1b = (const float*)d_in[15];
    const float* cm2  = (const float*)d_in[16];
    const float* cm2b = (const float*)d_in[17];
    const float* cm3  = (const float*)d_in[18];
    const float* cm3b = (const float*)d_in[19];
    const float* lu_wih = (const float*)d_in[20];
    const float* lu_whh = (const float*)d_in[21];
    const float* lu_bih = (const float*)d_in[22];
    const float* lu_bhh = (const float*)d_in[23];
    const float* cu_wih = (const float*)d_in[24];
    const float* cu_whh = (const float*)d_in[25];
    const float* cu_bih = (const float*)d_in[26];
    const float* cu_bhh = (const float*)d_in[27];
    const float* lv1  = (const float*)d_in[28];
    const float* lv1b = (const float*)d_in[29];
    const float* lv2  = (const float*)d_in[30];
    const float* lv2b = (const float*)d_in[31];
    const float* lv3  = (const float*)d_in[32];
    const float* lv3b = (const float*)d_in[33];

    float* F = (float*)d_ws;
    size_t o = 0;
    auto A = [&](size_t n) { float* p = F + o; o += n; return p; };
    float* outA  = A((size_t)NLIT_ * 64);
    float* outB  = A((size_t)NLIT_ * 64);
    float* outc0 = A((size_t)NCLS_ * 64);
    float* chA   = A((size_t)NCLS_ * 64);
    float* chB   = A((size_t)NCLS_ * 64);
    float* ccg   = A((size_t)NCLS_ * 64);
    float* lcg   = A((size_t)NLIT_ * 64);
    float* Wl    = A(4096);
    float* Wc    = A(4096);
    float* bl    = A(64);
    float* bc    = A(64);
    float* Wv    = A(64);
    float* bv    = A(16);
    float* Wfl   = A(64 * 256);
    float* bfl   = A(256);
    float* Bl    = A(256);
    float* Wfc   = A(64 * 256);
    float* Bc    = A(256);
    float* Tbuf  = A(2 * 4096);
    float* ubuf  = A(2 * 64);
    int* I = (int*)(F + o);
    int* llits  = I; I += NE_;
    int* rowptr = I; I += 12804;
    int* cursor = I; I += NLIT_;
    int* colA_  = I; I += NE_;
    int* cnt    = I; I += NLIT_;

    hipMemsetAsync(cnt, 0, NLIT_ * sizeof(int), stream);
    hipMemsetAsync(d_out, 0, (size_t)NN_ * sizeof(float), stream);

    collapseT_k<<<128, 64, 0, stream>>>(lm1, lm1b, lm2, lm2b, cm1, cm1b, cm2, cm2b, Tbuf, ubuf);
    collapseW_k<<<128, 64, 0, stream>>>(lm3, lm3b, cm3, cm3b, Tbuf, ubuf, Wl, bl, Wc, bc);
    votecol_k<<<1, 64, 0, stream>>>(lv1, lv1b, lv2, lv2b, lv3, lv3b, Wv, bv);
    fold2_k<<<128, 256, 0, stream>>>(Wl, bl, Wc, bc,
                                     lu_wih, lu_bih, lu_bhh,
                                     cu_wih, cu_bih, cu_bhh,
                                     Wfl, bfl, Bl, Wfc, Bc);
    init_k<<<(NN_ * 64 + 255) / 256, 256, 0, stream>>>(x, liw, lib, ciw, cib, outA, outc0);
    econv_k<<<NE_ / 256, 256, 0, stream>>>(ei, llits, cnt);
    scan_k<<<1, 1024, 0, stream>>>(cnt, rowptr, cursor);
    fill_k<<<NE_ / 256, 256, 0, stream>>>(llits, cursor, colA_);

    for (int s = 0; s < STEPS_; ++s) {
        const float* oc = (s & 1) ? outB : outA;
        float*       on = (s & 1) ? outA : outB;
        float*       chc = (s & 1) ? chA : chB;
        const float* chp = (s & 1) ? chB : chA;
        clause_step_k<<<110, 512, 0, stream>>>(oc, outc0, chc, chp, ccg,
                                               llits, Wfc, cu_whh, Bc, s);
        lit_step_k<<<200, 512, 0, stream>>>(oc, on, chc, lcg, rowptr, colA_,
                                            lu_wih, lu_whh, Wfl, bfl, Bl,
                                            Wv, bv, (float*)d_out, s);
    }
}

// Round 12
// 1910.701 us; speedup vs baseline: 1.1264x; 1.1264x over previous
//
#include <hip/hip_runtime.h>
#include <math.h>

// NeuroSAT, MI355X. Round 12: register-tiled gemm (R8xC8), VALU-bound.
//  - r3-r11 were LDS-BW-bound: per-CU LDS port is shared by all waves; old
//    tile (R=1/2, C=16) gave 0.47-0.89 FLOP per LDS byte -> ~6x LDS-bound.
//    New tile: 8 rows x 8 cols/thread: row reads broadcast across the 16
//    col-threads, weight reads sweep 32 banks 2-way -> 2.0 FLOP/B, VALU-bound.
//  - Weights pre-transformed once into [half][k][u*64+c*4+g] so staging is a
//    linear f4 copy and reads are conflict-free.
//  - CSR gather padded to x8 with a zeroed dummy chg row: branch-free batches.
//  - k-ascending FMA order per output preserved -> absmax ~0.0117 (as r11).
//  - 2 dispatches/step: clause 220 blk x 256 thr (64 rows, R=4),
//    lit 200 blk x 256 thr (128 rows, R=8).

#define NV2_   800
#define NC_    440
#define KK_    12
#define NPG_   1240
#define NLIT_  12800
#define NCLS_  7040
#define NE_    84480
#define NN_    19840
#define STEPS_ 23

__device__ __forceinline__ float sigmf(float x) { return 1.0f / (1.0f + __expf(-x)); }
__device__ __forceinline__ float tanhf_(float x) { return 1.0f - 2.0f / (__expf(2.0f * x) + 1.0f); }

// ---------------- setup kernels ----------------

__global__ __launch_bounds__(64) void collapseT_k(
    const float* lm1, const float* lm1b, const float* lm2, const float* lm2b,
    const float* cm1, const float* cm1b, const float* cm2, const float* cm2b,
    float* T, float* ub)
{
    int r = blockIdx.x >> 6, i = blockIdx.x & 63, j = threadIdx.x;
    const float* w1 = r ? cm1 : lm1; const float* b1 = r ? cm1b : lm1b;
    const float* w2 = r ? cm2 : lm2; const float* b2 = r ? cm2b : lm2b;
    float s = 0.f;
    for (int k = 0; k < 64; ++k) s += w1[i * 64 + k] * w2[k * 64 + j];
    T[r * 4096 + i * 64 + j] = s;
    if (i == 0) {
        float s2 = 0.f;
        for (int k = 0; k < 64; ++k) s2 += b1[k] * w2[k * 64 + j];
        ub[r * 64 + j] = s2 + b2[j];
    }
}

__global__ __launch_bounds__(64) void collapseW_k(
    const float* lm3, const float* lm3b, const float* cm3, const float* cm3b,
    const float* T, const float* ub,
    float* Wl, float* bl, float* Wc, float* bc)
{
    int r = blockIdx.x >> 6, i = blockIdx.x & 63, j = threadIdx.x;
    const float* w3 = r ? cm3 : lm3; const float* b3 = r ? cm3b : lm3b;
    float* W = r ? Wc : Wl; float* bb = r ? bc : bl;
    float s = 0.f;
    for (int k = 0; k < 64; ++k) s += T[r * 4096 + i * 64 + k] * w3[k * 64 + j];
    W[i * 64 + j] = s;
    if (i == 0) {
        float s2 = 0.f;
        for (int k = 0; k < 64; ++k) s2 += ub[r * 64 + k] * w3[k * 64 + j];
        bb[j] = s2 + b3[j];
    }
}

__global__ __launch_bounds__(64) void votecol_k(
    const float* lv1, const float* lv1b, const float* lv2, const float* lv2b,
    const float* lv3, const float* lv3b, float* Wv, float* bv)
{
    __shared__ float t3[64];
    __shared__ float ub2[64];
    int t = threadIdx.x;
    float s = 0.f;
    for (int j = 0; j < 64; ++j) s += lv2[t * 64 + j] * lv3[j];
    t3[t] = s;
    float s2 = 0.f;
    for (int k = 0; k < 64; ++k) s2 += lv1b[k] * lv2[k * 64 + t];
    ub2[t] = s2 + lv2b[t];
    __syncthreads();
    float s3 = 0.f;
    for (int k = 0; k < 64; ++k) s3 += lv1[t * 64 + k] * t3[k];
    Wv[t] = s3;
    if (t == 0) {
        float v = 0.f;
        for (int j = 0; j < 64; ++j) v += ub2[j] * lv3[j];
        bv[0] = v + lv3b[0];
    }
}

__global__ __launch_bounds__(256) void fold2_k(
    const float* Wl, const float* bl, const float* Wc, const float* bc,
    const float* lwih, const float* lbih, const float* lbhh,
    const float* cwih, const float* cbih, const float* cbhh,
    float* Wfl, float* bfl, float* Bl, float* Wfc, float* Bc)
{
    int t = blockIdx.x >> 6, i = blockIdx.x & 63, j = threadIdx.x;
    if (t == 0) {
        float s = 0.f;
        for (int m = 0; m < 64; ++m) s += Wc[i * 64 + m] * lwih[(64 + m) * 256 + j];
        Wfl[i * 256 + j] = s;
        if (i == 0) {
            float s2 = 0.f;
            for (int m = 0; m < 64; ++m) s2 += bc[m] * lwih[(64 + m) * 256 + j];
            bfl[j] = s2;
            Bl[j] = lbih[j] + lbhh[j];
        }
    } else {
        float s = 0.f;
        for (int m = 0; m < 64; ++m) s += Wl[i * 64 + m] * cwih[m * 256 + j];
        Wfc[i * 256 + j] = s;
        if (i == 0) {
            float s2 = 0.f;
            for (int m = 0; m < 64; ++m) s2 += bl[m] * cwih[m * 256 + j];
            Bc[j] = cbih[j] + cbhh[j] + 13.f * s2;
        }
    }
}

// transform [64][256] -> [half][64][u*64 + c*4 + g]; col = g*64 + half*32 + 2c + u
__global__ __launch_bounds__(128) void wtrans_k(const float* src, float* dst)
{
    int k = blockIdx.x & 63, half = blockIdx.x >> 6;
    int r = threadIdx.x;
    int u = r >> 6, c = (r >> 2) & 15, g = r & 3;
    dst[(half * 64 + k) * 128 + r] = src[k * 256 + g * 64 + half * 32 + 2 * c + u];
}

__global__ __launch_bounds__(256) void init_k(
    const float* x, const float* liw, const float* lib, const float* ciw, const float* cib,
    float* out0, float* outc)
{
    int t = blockIdx.x * 256 + threadIdx.x;
    if (t >= NN_ * 64) return;
    int node = t >> 6, j = t & 63;
    int b = node / NPG_;
    int i = node - b * NPG_;
    float x0 = x[node * 2 + 0], x1 = x[node * 2 + 1];
    if (i < NV2_) {
        int sp = (i < 400) ? 2 * i : 2 * (i - 400) + 1;
        out0[(size_t)(b * NV2_ + sp) * 64 + j] = x0 * liw[j] + x1 * liw[64 + j] + lib[j];
    } else {
        outc[(size_t)(b * NC_ + (i - NV2_)) * 64 + j] = x0 * ciw[j] + x1 * ciw[64 + j] + cib[j];
    }
}

__global__ __launch_bounds__(256) void econv_k(const int* ei, int* llits, int* cnt)
{
    int e = blockIdx.x * 256 + threadIdx.x;
    if (e >= NE_) return;
    int g = ei[e];
    int b = g / NPG_;
    int i = g - b * NPG_;
    int sp = (i < 400) ? 2 * i : 2 * (i - 400) + 1;
    int L = b * NV2_ + sp;
    llits[e] = L;
    atomicAdd(cnt + L, 1);
}

// padded scan: slot size = ceil(cnt/8)*8
__global__ __launch_bounds__(1024) void scan_k(const int* cnt, int* rowptr, int* cursor)
{
    __shared__ int sums[1024];
    int t = threadIdx.x;
    int i0 = t * 13;
    int i1 = i0 + 13; if (i1 > NLIT_) i1 = NLIT_; if (i0 > NLIT_) i0 = NLIT_;
    int s = 0;
    for (int i = i0; i < i1; ++i) s += (cnt[i] + 7) & ~7;
    sums[t] = s;
    __syncthreads();
    for (int off = 1; off < 1024; off <<= 1) {
        int v = (t >= off) ? sums[t - off] : 0;
        __syncthreads();
        sums[t] += v;
        __syncthreads();
    }
    int run = sums[t] - s;
    for (int i = i0; i < i1; ++i) {
        rowptr[i] = run; cursor[i] = run;
        run += (cnt[i] + 7) & ~7;
    }
    if (t == 1023) rowptr[NLIT_] = sums[1023];
}

__global__ __launch_bounds__(256) void fill_k(const int* llits, int* cursor, int* col)
{
    int e = blockIdx.x * 256 + threadIdx.x;
    if (e >= NE_) return;
    int pos = atomicAdd(cursor + llits[e], 1);
    col[pos] = e / KK_;
}

// fill pad region of each row with dummy clause NCLS_
__global__ __launch_bounds__(256) void pad_k(const int* cnt, const int* rowptr, int* col)
{
    int i = blockIdx.x * 256 + threadIdx.x;
    if (i >= NLIT_) return;
    for (int e = rowptr[i] + cnt[i]; e < rowptr[i + 1]; ++e) col[e] = NCLS_;
}

// ---------------- register-tiled gemm ----------------
// acc[rr*8 + u*4 + g] += sum_k Ls[((r0+rr)^rx)*64 + k] * wS[k*128 + u*64 + c*4 + g]
template<int R>
__device__ __forceinline__ void gemmR8(const float* __restrict__ Ls, int r0, int rx,
                                       const float* __restrict__ wS, int c, float* acc)
{
#pragma unroll 2
    for (int k4 = 0; k4 < 16; ++k4) {
        float4 rf[R];
#pragma unroll
        for (int rr = 0; rr < R; ++rr)
            rf[rr] = *(const float4*)(Ls + ((r0 + rr) ^ rx) * 64 + k4 * 4);
#pragma unroll
        for (int kk = 0; kk < 4; ++kk) {
            const float* wp = wS + (k4 * 4 + kk) * 128 + c * 4;
            float4 w0 = *(const float4*)(wp);
            float4 w1 = *(const float4*)(wp + 64);
#pragma unroll
            for (int rr = 0; rr < R; ++rr) {
                float in = (kk == 0) ? rf[rr].x : (kk == 1) ? rf[rr].y
                         : (kk == 2) ? rf[rr].z : rf[rr].w;
                acc[rr * 8 + 0] = fmaf(in, w0.x, acc[rr * 8 + 0]);
                acc[rr * 8 + 1] = fmaf(in, w0.y, acc[rr * 8 + 1]);
                acc[rr * 8 + 2] = fmaf(in, w0.z, acc[rr * 8 + 2]);
                acc[rr * 8 + 3] = fmaf(in, w0.w, acc[rr * 8 + 3]);
                acc[rr * 8 + 4] = fmaf(in, w1.x, acc[rr * 8 + 4]);
                acc[rr * 8 + 5] = fmaf(in, w1.y, acc[rr * 8 + 5]);
                acc[rr * 8 + 6] = fmaf(in, w1.z, acc[rr * 8 + 6]);
                acc[rr * 8 + 7] = fmaf(in, w1.w, acc[rr * 8 + 7]);
            }
        }
    }
}

// gates i,f,g,o for one (row, unit): a = acc + rr*8 + u*4
__device__ __forceinline__ void cellu(const float* a, float* c, float* h)
{
    float iv = sigmf(a[0]);
    float fv = sigmf(a[1]);
    float gv = tanhf_(a[2]);
    float ov = sigmf(a[3]);
    float c2 = fv * (*c) + iv * gv;
    *c = c2;
    *h = ov * tanhf_(c2);
}

// ---------------- per-step kernels ----------------

// clause: 220 blocks (110 rowgrps x 2 halves) x 256 thr, 64 rows, R=4.
__global__ __launch_bounds__(256) void clause_step_k(
    const float* __restrict__ out_cur, const float* __restrict__ outc0,
    float* __restrict__ ch_cur, const float* __restrict__ ch_prev, float* __restrict__ ccg,
    const int* __restrict__ llits,
    const float* __restrict__ wfcT, const float* __restrict__ cwhhT,
    const float* __restrict__ Bc, int step)
{
    __shared__ float whh_s[8192];
    __shared__ float wfc_s[8192];
    __shared__ float LM[64 * 64];
    __shared__ float CH[64 * 64];
    const int tid = threadIdx.x;
    const int lane = tid & 63;
    const int wv = tid >> 6;                 // 0..3
    const int half = blockIdx.x & 1;
    const int U0 = half * 32;
    const int Cb = (blockIdx.x >> 1) * 64;

    // stage transformed weights (linear f4)
    {
        const float4* wfp = (const float4*)(wfcT + half * 8192);
        const float4* whp = (const float4*)(cwhhT + half * 8192);
        for (int i = tid; i < 2048; i += 256) {
            ((float4*)wfc_s)[i] = wfp[i];
            ((float4*)whh_s)[i] = whp[i];
        }
    }
    // gather: 4 waves x 16 rows, lane = column
    for (int j = 0; j < 16; ++j) {
        int srow = wv * 16 + j;
        int cc_ = Cb + srow;
        float v;
        if (step) {
            float ch0 = ch_prev[(size_t)cc_ * 64 + lane];
            CH[srow * 64 + lane] = ch0;
            v = ch0;
        } else {
            v = outc0[(size_t)cc_ * 64 + lane];
        }
        const int* lp = llits + cc_ * KK_;
        float t0 = out_cur[(size_t)lp[0] * 64 + lane];
        float t1 = out_cur[(size_t)lp[1] * 64 + lane];
        float t2 = out_cur[(size_t)lp[2] * 64 + lane];
        float t3 = out_cur[(size_t)lp[3] * 64 + lane];
        float t4 = out_cur[(size_t)lp[4] * 64 + lane];
        float t5 = out_cur[(size_t)lp[5] * 64 + lane];
        float t6 = out_cur[(size_t)lp[6] * 64 + lane];
        float t7 = out_cur[(size_t)lp[7] * 64 + lane];
        float t8 = out_cur[(size_t)lp[8] * 64 + lane];
        float t9 = out_cur[(size_t)lp[9] * 64 + lane];
        float ta = out_cur[(size_t)lp[10] * 64 + lane];
        float tb = out_cur[(size_t)lp[11] * 64 + lane];
        v += t0 + t1 + t2 + t3 + t4 + t5 + t6 + t7 + t8 + t9 + ta + tb;
        LM[srow * 64 + lane] = v;
    }
    __syncthreads();

    const int c = tid & 15;
    const int r0 = (tid >> 4) * 4;
    float acc[32];
    if (step) {
#pragma unroll
        for (int i = 0; i < 32; ++i) acc[i] = 0.f;
        gemmR8<4>(CH, r0, 0, whh_s, c, acc);      // ch(s-1) @ whh
#pragma unroll
        for (int rr = 0; rr < 4; ++rr)
#pragma unroll
            for (int u = 0; u < 2; ++u)
#pragma unroll
                for (int g = 0; g < 4; ++g)
                    acc[rr * 8 + u * 4 + g] += Bc[g * 64 + U0 + 2 * c + u];
    } else {
#pragma unroll
        for (int rr = 0; rr < 4; ++rr)
#pragma unroll
            for (int u = 0; u < 2; ++u)
#pragma unroll
                for (int g = 0; g < 4; ++g)
                    acc[rr * 8 + u * 4 + g] = Bc[g * 64 + U0 + 2 * c + u];
    }
    gemmR8<4>(LM, r0, 0, wfc_s, c, acc);          // folded l_msg

#pragma unroll
    for (int rr = 0; rr < 4; ++rr) {
        size_t rowoff = (size_t)(Cb + r0 + rr) * 64 + U0 + 2 * c;
        float cc0, cc1;
        if (step) {
            float2 cp = *(const float2*)(ccg + rowoff);
            cc0 = cp.x; cc1 = cp.y;
        } else { cc0 = 0.f; cc1 = 0.f; }
        float h0, h1;
        cellu(acc + rr * 8 + 0, &cc0, &h0);
        cellu(acc + rr * 8 + 4, &cc1, &h1);
        *(float2*)(ch_cur + rowoff) = make_float2(h0, h1);
        *(float2*)(ccg + rowoff) = make_float2(cc0, cc1);
    }
}

// lit: 200 blocks (100 rowgrps x 2 halves) x 256 thr, 128 rows, R=8.
__global__ __launch_bounds__(256) void lit_step_k(
    const float* __restrict__ out_cur, float* __restrict__ out_nxt,
    const float* __restrict__ chg, float* __restrict__ lcg,
    const int* __restrict__ rowptr, const int* __restrict__ col, const int* __restrict__ cnt,
    const float* __restrict__ wihT, const float* __restrict__ whhT, const float* __restrict__ wflT,
    const float* __restrict__ bfl, const float* __restrict__ Bl,
    const float* __restrict__ Wv, const float* __restrict__ bv, float* __restrict__ vout,
    int step)
{
    __shared__ float wih_s[8192];
    __shared__ float whh_s[8192];
    __shared__ float wfl_s[8192];
    __shared__ float buf[128 * 64];
    const int tid = threadIdx.x;
    const int lane = tid & 63;
    const int wv = tid >> 6;                 // 0..3
    const int half = blockIdx.x & 1;
    const int U0 = half * 32;
    const int Lb = (blockIdx.x >> 1) * 128;

    // stage transformed weights + out rows (linear f4)
    {
        const float4* wip = (const float4*)(wihT + half * 8192);
        const float4* whp = (const float4*)(whhT + half * 8192);
        const float4* wfp = (const float4*)(wflT + half * 8192);
        const float4* op  = (const float4*)(out_cur + (size_t)Lb * 64);
        for (int i = tid; i < 2048; i += 256) {
            ((float4*)wih_s)[i] = wip[i];
            ((float4*)whh_s)[i] = whp[i];
            ((float4*)wfl_s)[i] = wfp[i];
            ((float4*)buf)[i]   = op[i];
        }
    }
    __syncthreads();

    const int c = tid & 15;
    const int r0 = (tid >> 4) * 8;
    float acc[64];
#pragma unroll
    for (int rr = 0; rr < 8; ++rr) {
        float degf = 1.f + (float)cnt[Lb + r0 + rr];
#pragma unroll
        for (int u = 0; u < 2; ++u)
#pragma unroll
            for (int g = 0; g < 4; ++g) {
                int gc = g * 64 + U0 + 2 * c + u;
                acc[rr * 8 + u * 4 + g] = Bl[gc] + degf * bfl[gc];
            }
    }
    gemmR8<8>(buf, r0, 1, wih_s, c, acc);        // out[flip] @ wih_top (flip = row^1)
    if (step) gemmR8<8>(buf, r0, 0, whh_s, c, acc);  // lh @ whh
    __syncthreads();   // gemm reads of buf done before gather overwrites

    // padded CSR gather (deg multiple of 8, dummy row NCLS_ is zero): 4 waves x 32 rows
    for (int j = 0; j < 32; ++j) {
        int srow = wv * 32 + j;
        int l = Lb + srow;
        int e = rowptr[l], eE = rowptr[l + 1];
        float v = buf[srow * 64 + lane];
        for (; e < eE; e += 8) {
            float t0 = chg[(size_t)col[e    ] * 64 + lane];
            float t1 = chg[(size_t)col[e + 1] * 64 + lane];
            float t2 = chg[(size_t)col[e + 2] * 64 + lane];
            float t3 = chg[(size_t)col[e + 3] * 64 + lane];
            float t4 = chg[(size_t)col[e + 4] * 64 + lane];
            float t5 = chg[(size_t)col[e + 5] * 64 + lane];
            float t6 = chg[(size_t)col[e + 6] * 64 + lane];
            float t7 = chg[(size_t)col[e + 7] * 64 + lane];
            v += ((t0 + t1) + (t2 + t3)) + ((t4 + t5) + (t6 + t7));
        }
        buf[srow * 64 + lane] = v;
    }
    __syncthreads();
    gemmR8<8>(buf, r0, 0, wfl_s, c, acc);        // folded c_msg

    float h[8][2];
#pragma unroll
    for (int rr = 0; rr < 8; ++rr) {
        size_t rowoff = (size_t)(Lb + r0 + rr) * 64 + U0 + 2 * c;
        float lc0, lc1;
        if (step) {
            float2 cp = *(const float2*)(lcg + rowoff);
            lc0 = cp.x; lc1 = cp.y;
        } else { lc0 = 0.f; lc1 = 0.f; }
        cellu(acc + rr * 8 + 0, &lc0, &h[rr][0]);
        cellu(acc + rr * 8 + 4, &lc1, &h[rr][1]);
        *(float2*)(out_nxt + rowoff) = make_float2(h[rr][0], h[rr][1]);
        *(float2*)(lcg + rowoff) = make_float2(lc0, lc1);
    }

    if (step == STEPS_ - 1) {
        // vote: stage per-thread partials in reused weight LDS, reduce per row
        float wv0 = Wv[U0 + 2 * c], wv1 = Wv[U0 + 2 * c + 1];
        __syncthreads();
        float* pbuf = wih_s;   // 128 rows x 16 cols
#pragma unroll
        for (int rr = 0; rr < 8; ++rr)
            pbuf[(r0 + rr) * 16 + c] = h[rr][0] * wv0 + h[rr][1] * wv1;
        __syncthreads();
        if (tid < 128) {
            int row = tid;
            float v = (half == 0) ? bv[0] : 0.f;
#pragma unroll
            for (int q = 0; q < 16; ++q) v += pbuf[row * 16 + q];
            int R = Lb + row;
            int b = R / NV2_;
            int pos = R - b * NV2_;
            int pi = (pos >> 1) + (pos & 1) * 400;   // undo pair-interleave
            atomicAdd(vout + b * NPG_ + pi, v);
        }
    }
}

// ---------------- host ----------------

extern "C" void kernel_launch(void* const* d_in, const int* in_sizes, int n_in,
                              void* d_out, int out_size, void* d_ws, size_t ws_size,
                              hipStream_t stream)
{
    (void)in_sizes; (void)n_in; (void)out_size; (void)ws_size;
    const float* x    = (const float*)d_in[0];
    const int*   ei   = (const int*)d_in[2];
    const float* liw  = (const float*)d_in[4];
    const float* lib  = (const float*)d_in[5];
    const float* ciw  = (const float*)d_in[6];
    const float* cib  = (const float*)d_in[7];
    const float* lm1  = (const float*)d_in[8];
    const float* lm1b = (const float*)d_in[9];
    const float* lm2  = (const float*)d_in[10];
    const float* lm2b = (const float*)d_in[11];
    const float* lm3  = (const float*)d_in[12];
    const float* lm3b = (const float*)d_in[13];
    const float* cm1  = (const float*)d_in[14];
    const float* cm1b = (const float*)d_in[15];
    const float* cm2  = (const float*)d_in[16];
    const float* cm2b = (const float*)d_in[17];
    const float* cm3  = (const float*)d_in[18];
    const float* cm3b = (const float*)d_in[19];
    const float* lu_wih = (const float*)d_in[20];
    const float* lu_whh = (const float*)d_in[21];
    const float* lu_bih = (const float*)d_in[22];
    const float* lu_bhh = (const float*)d_in[23];
    const float* cu_wih = (const float*)d_in[24];
    const float* cu_whh = (const float*)d_in[25];
    const float* cu_bih = (const float*)d_in[26];
    const float* cu_bhh = (const float*)d_in[27];
    const float* lv1  = (const float*)d_in[28];
    const float* lv1b = (const float*)d_in[29];
    const float* lv2  = (const float*)d_in[30];
    const float* lv2b = (const float*)d_in[31];
    const float* lv3  = (const float*)d_in[32];
    const float* lv3b = (const float*)d_in[33];

    float* F = (float*)d_ws;
    size_t o = 0;
    auto A = [&](size_t n) { float* p = F + o; o += n; return p; };
    float* outA  = A((size_t)NLIT_ * 64);
    float* outB  = A((size_t)NLIT_ * 64);
    float* outc0 = A((size_t)NCLS_ * 64);
    float* chA   = A((size_t)(NCLS_ + 1) * 64);   // +1 dummy zero row
    float* chB   = A((size_t)(NCLS_ + 1) * 64);
    float* ccg   = A((size_t)NCLS_ * 64);
    float* lcg   = A((size_t)NLIT_ * 64);
    float* Wl    = A(4096);
    float* Wc    = A(4096);
    float* bl    = A(64);
    float* bc    = A(64);
    float* Wv    = A(64);
    float* bv    = A(16);
    float* Wfl   = A(64 * 256);
    float* bfl   = A(256);
    float* Bl    = A(256);
    float* Wfc   = A(64 * 256);
    float* Bc    = A(256);
    float* Tbuf  = A(2 * 4096);
    float* ubuf  = A(2 * 64);
    float* wihT  = A(16384);
    float* whhT  = A(16384);
    float* wflT  = A(16384);
    float* cwhhT = A(16384);
    float* wfcT  = A(16384);
    int* I = (int*)(F + o);
    int* llits  = I; I += NE_;
    int* rowptr = I; I += 12804;
    int* cursor = I; I += NLIT_;
    int* pcol   = I; I += 184320;   // padded CSR cols
    int* cnt    = I; I += NLIT_;

    hipMemsetAsync(cnt, 0, NLIT_ * sizeof(int), stream);
    hipMemsetAsync(chA + (size_t)NCLS_ * 64, 0, 64 * sizeof(float), stream);
    hipMemsetAsync(chB + (size_t)NCLS_ * 64, 0, 64 * sizeof(float), stream);
    hipMemsetAsync(d_out, 0, (size_t)NN_ * sizeof(float), stream);

    collapseT_k<<<128, 64, 0, stream>>>(lm1, lm1b, lm2, lm2b, cm1, cm1b, cm2, cm2b, Tbuf, ubuf);
    collapseW_k<<<128, 64, 0, stream>>>(lm3, lm3b, cm3, cm3b, Tbuf, ubuf, Wl, bl, Wc, bc);
    votecol_k<<<1, 64, 0, stream>>>(lv1, lv1b, lv2, lv2b, lv3, lv3b, Wv, bv);
    fold2_k<<<128, 256, 0, stream>>>(Wl, bl, Wc, bc,
                                     lu_wih, lu_bih, lu_bhh,
                                     cu_wih, cu_bih, cu_bhh,
                                     Wfl, bfl, Bl, Wfc, Bc);
    wtrans_k<<<128, 128, 0, stream>>>(lu_wih, wihT);
    wtrans_k<<<128, 128, 0, stream>>>(lu_whh, whhT);
    wtrans_k<<<128, 128, 0, stream>>>(Wfl, wflT);
    wtrans_k<<<128, 128, 0, stream>>>(cu_whh, cwhhT);
    wtrans_k<<<128, 128, 0, stream>>>(Wfc, wfcT);
    init_k<<<(NN_ * 64 + 255) / 256, 256, 0, stream>>>(x, liw, lib, ciw, cib, outA, outc0);
    econv_k<<<NE_ / 256, 256, 0, stream>>>(ei, llits, cnt);
    scan_k<<<1, 1024, 0, stream>>>(cnt, rowptr, cursor);
    fill_k<<<NE_ / 256, 256, 0, stream>>>(llits, cursor, pcol);
    pad_k<<<(NLIT_ + 255) / 256, 256, 0, stream>>>(cnt, rowptr, pcol);

    for (int s = 0; s < STEPS_; ++s) {
        const float* oc  = (s & 1) ? outB : outA;
        float*       on  = (s & 1) ? outA : outB;
        float*       chc = (s & 1) ? chA : chB;
        const float* chp = (s & 1) ? chB : chA;
        clause_step_k<<<220, 256, 0, stream>>>(oc, outc0, chc, chp, ccg,
                                               llits, wfcT, cwhhT, Bc, s);
        lit_step_k<<<200, 256, 0, stream>>>(oc, on, chc, lcg, rowptr, pcol, cnt,
                                            wihT, whhT, wflT, bfl, Bl,
                                            Wv, bv, (float*)d_out, s);
    }
}

// Round 13
// 1369.580 us; speedup vs baseline: 1.5714x; 1.3951x over previous
//
#include <hip/hip_runtime.h>
#include <math.h>

// NeuroSAT, MI355X. Round 13: scalar-pipe weights (s_load), lane=row gemm.
//  - r3-r12 lesson: LDS-broadcast weights are LDS-pipe-bound at ANY occupancy
//    (16 b128/k4 = 192 LDS-cy vs 128 VALU-cy/SIMD). Weights are lane-invariant
//    with lane=row -> stream them into SGPRs via s_load_dwordx8 (SMEM pipe).
//    Inputs come from a transposed LDS tile bufT[k][r] (stride 65, conflict-
//    free b32). Per k: 1 ds_read_b32 + 16 FMA -> VALU-bound, 5x LDS headroom.
//  - 512-thr blocks (8 waves = 8 col-chunks of 4 units), 64 rows, lane=row.
//    LDS 19-33KB -> ~2 blocks/CU at <=128 VGPR.
//  - h/c/out writes staged in LDS, stored as dense 128B row-halves.
//  - FMA order identical to r12 -> absmax exactly 0.01171875 (vote +-ulp).

#define NV2_   800
#define NC_    440
#define KK_    12
#define NPG_   1240
#define NLIT_  12800
#define NCLS_  7040
#define NE_    84480
#define NN_    19840
#define STEPS_ 23

typedef __attribute__((ext_vector_type(8))) float fx8;

__device__ __forceinline__ float sigmf(float x) { return 1.0f / (1.0f + __expf(-x)); }
__device__ __forceinline__ float tanhf_(float x) { return 1.0f - 2.0f / (__expf(2.0f * x) + 1.0f); }

// ---------------- setup kernels ----------------

__global__ __launch_bounds__(64) void collapseT_k(
    const float* lm1, const float* lm1b, const float* lm2, const float* lm2b,
    const float* cm1, const float* cm1b, const float* cm2, const float* cm2b,
    float* T, float* ub)
{
    int r = blockIdx.x >> 6, i = blockIdx.x & 63, j = threadIdx.x;
    const float* w1 = r ? cm1 : lm1; const float* b1 = r ? cm1b : lm1b;
    const float* w2 = r ? cm2 : lm2; const float* b2 = r ? cm2b : lm2b;
    float s = 0.f;
    for (int k = 0; k < 64; ++k) s += w1[i * 64 + k] * w2[k * 64 + j];
    T[r * 4096 + i * 64 + j] = s;
    if (i == 0) {
        float s2 = 0.f;
        for (int k = 0; k < 64; ++k) s2 += b1[k] * w2[k * 64 + j];
        ub[r * 64 + j] = s2 + b2[j];
    }
}

__global__ __launch_bounds__(64) void collapseW_k(
    const float* lm3, const float* lm3b, const float* cm3, const float* cm3b,
    const float* T, const float* ub,
    float* Wl, float* bl, float* Wc, float* bc)
{
    int r = blockIdx.x >> 6, i = blockIdx.x & 63, j = threadIdx.x;
    const float* w3 = r ? cm3 : lm3; const float* b3 = r ? cm3b : lm3b;
    float* W = r ? Wc : Wl; float* bb = r ? bc : bl;
    float s = 0.f;
    for (int k = 0; k < 64; ++k) s += T[r * 4096 + i * 64 + k] * w3[k * 64 + j];
    W[i * 64 + j] = s;
    if (i == 0) {
        float s2 = 0.f;
        for (int k = 0; k < 64; ++k) s2 += ub[r * 64 + k] * w3[k * 64 + j];
        bb[j] = s2 + b3[j];
    }
}

__global__ __launch_bounds__(64) void votecol_k(
    const float* lv1, const float* lv1b, const float* lv2, const float* lv2b,
    const float* lv3, const float* lv3b, float* Wv, float* bv)
{
    __shared__ float t3[64];
    __shared__ float ub2[64];
    int t = threadIdx.x;
    float s = 0.f;
    for (int j = 0; j < 64; ++j) s += lv2[t * 64 + j] * lv3[j];
    t3[t] = s;
    float s2 = 0.f;
    for (int k = 0; k < 64; ++k) s2 += lv1b[k] * lv2[k * 64 + t];
    ub2[t] = s2 + lv2b[t];
    __syncthreads();
    float s3 = 0.f;
    for (int k = 0; k < 64; ++k) s3 += lv1[t * 64 + k] * t3[k];
    Wv[t] = s3;
    if (t == 0) {
        float v = 0.f;
        for (int j = 0; j < 64; ++j) v += ub2[j] * lv3[j];
        bv[0] = v + lv3b[0];
    }
}

__global__ __launch_bounds__(256) void fold2_k(
    const float* Wl, const float* bl, const float* Wc, const float* bc,
    const float* lwih, const float* lbih, const float* lbhh,
    const float* cwih, const float* cbih, const float* cbhh,
    float* Wfl, float* bfl, float* Bl, float* Wfc, float* Bc)
{
    int t = blockIdx.x >> 6, i = blockIdx.x & 63, j = threadIdx.x;
    if (t == 0) {
        float s = 0.f;
        for (int m = 0; m < 64; ++m) s += Wc[i * 64 + m] * lwih[(64 + m) * 256 + j];
        Wfl[i * 256 + j] = s;
        if (i == 0) {
            float s2 = 0.f;
            for (int m = 0; m < 64; ++m) s2 += bc[m] * lwih[(64 + m) * 256 + j];
            bfl[j] = s2;
            Bl[j] = lbih[j] + lbhh[j];
        }
    } else {
        float s = 0.f;
        for (int m = 0; m < 64; ++m) s += Wl[i * 64 + m] * cwih[m * 256 + j];
        Wfc[i * 256 + j] = s;
        if (i == 0) {
            float s2 = 0.f;
            for (int m = 0; m < 64; ++m) s2 += bl[m] * cwih[m * 256 + j];
            Bc[j] = cbih[j] + cbhh[j] + 13.f * s2;
        }
    }
}

// [64][256] -> [half*8+chunk][k][u4*4+g];  col = g*64 + half*32 + chunk*4 + u4
__global__ __launch_bounds__(1024) void wtrans2_k(const float* src, float* dst)
{
    int hc = blockIdx.x;            // 0..15
    int half = hc >> 3, chunk = hc & 7;
    int t = threadIdx.x;
    int k = t >> 4, u4 = (t >> 2) & 3, g = t & 3;
    dst[(hc * 64 + k) * 16 + u4 * 4 + g] = src[k * 256 + g * 64 + half * 32 + chunk * 4 + u4];
}

__global__ __launch_bounds__(256) void init_k(
    const float* x, const float* liw, const float* lib, const float* ciw, const float* cib,
    float* out0, float* outc)
{
    int t = blockIdx.x * 256 + threadIdx.x;
    if (t >= NN_ * 64) return;
    int node = t >> 6, j = t & 63;
    int b = node / NPG_;
    int i = node - b * NPG_;
    float x0 = x[node * 2 + 0], x1 = x[node * 2 + 1];
    if (i < NV2_) {
        int sp = (i < 400) ? 2 * i : 2 * (i - 400) + 1;
        out0[(size_t)(b * NV2_ + sp) * 64 + j] = x0 * liw[j] + x1 * liw[64 + j] + lib[j];
    } else {
        outc[(size_t)(b * NC_ + (i - NV2_)) * 64 + j] = x0 * ciw[j] + x1 * ciw[64 + j] + cib[j];
    }
}

__global__ __launch_bounds__(256) void econv_k(const int* ei, int* llits, int* cnt)
{
    int e = blockIdx.x * 256 + threadIdx.x;
    if (e >= NE_) return;
    int g = ei[e];
    int b = g / NPG_;
    int i = g - b * NPG_;
    int sp = (i < 400) ? 2 * i : 2 * (i - 400) + 1;
    int L = b * NV2_ + sp;
    llits[e] = L;
    atomicAdd(cnt + L, 1);
}

__global__ __launch_bounds__(1024) void scan_k(const int* cnt, int* rowptr, int* cursor)
{
    __shared__ int sums[1024];
    int t = threadIdx.x;
    int i0 = t * 13;
    int i1 = i0 + 13; if (i1 > NLIT_) i1 = NLIT_; if (i0 > NLIT_) i0 = NLIT_;
    int s = 0;
    for (int i = i0; i < i1; ++i) s += (cnt[i] + 7) & ~7;
    sums[t] = s;
    __syncthreads();
    for (int off = 1; off < 1024; off <<= 1) {
        int v = (t >= off) ? sums[t - off] : 0;
        __syncthreads();
        sums[t] += v;
        __syncthreads();
    }
    int run = sums[t] - s;
    for (int i = i0; i < i1; ++i) {
        rowptr[i] = run; cursor[i] = run;
        run += (cnt[i] + 7) & ~7;
    }
    if (t == 1023) rowptr[NLIT_] = sums[1023];
}

__global__ __launch_bounds__(256) void fill_k(const int* llits, int* cursor, int* col)
{
    int e = blockIdx.x * 256 + threadIdx.x;
    if (e >= NE_) return;
    int pos = atomicAdd(cursor + llits[e], 1);
    col[pos] = e / KK_;
}

__global__ __launch_bounds__(256) void pad_k(const int* cnt, const int* rowptr, int* col)
{
    int i = blockIdx.x * 256 + threadIdx.x;
    if (i >= NLIT_) return;
    for (int e = rowptr[i] + cnt[i]; e < rowptr[i + 1]; ++e) col[e] = NCLS_;
}

// ---------------- scalar-weight gemm ----------------
// acc[u4*4+g] += sum_k bufT[k*65 + (lane^rx)] * Wt[(k)*16 + u4*4+g]
// Wt slice (4KB) streamed via s_load_dwordx8 into SGPRs (lane-invariant).
#define FMA8(rv, w, off) \
    acc[(off)+0] = fmaf(rv, (w)[0], acc[(off)+0]); \
    acc[(off)+1] = fmaf(rv, (w)[1], acc[(off)+1]); \
    acc[(off)+2] = fmaf(rv, (w)[2], acc[(off)+2]); \
    acc[(off)+3] = fmaf(rv, (w)[3], acc[(off)+3]); \
    acc[(off)+4] = fmaf(rv, (w)[4], acc[(off)+4]); \
    acc[(off)+5] = fmaf(rv, (w)[5], acc[(off)+5]); \
    acc[(off)+6] = fmaf(rv, (w)[6], acc[(off)+6]); \
    acc[(off)+7] = fmaf(rv, (w)[7], acc[(off)+7]);

__device__ __forceinline__ void gemmS(const float* __restrict__ Ls, int rx,
                                      const float* __restrict__ wb, float* acc)
{
    const int r = (threadIdx.x & 63) ^ rx;
#pragma unroll 1
    for (int k4 = 0; k4 < 16; ++k4) {
        float rf0 = Ls[(k4 * 4 + 0) * 65 + r];
        float rf1 = Ls[(k4 * 4 + 1) * 65 + r];
        float rf2 = Ls[(k4 * 4 + 2) * 65 + r];
        float rf3 = Ls[(k4 * 4 + 3) * 65 + r];
        fx8 w0, w1, w2, w3, w4, w5, w6, w7;
        const float* p = wb + k4 * 64;
        asm volatile(
            "s_load_dwordx8 %0, %8, 0x0\n\t"
            "s_load_dwordx8 %1, %8, 0x20\n\t"
            "s_load_dwordx8 %2, %8, 0x40\n\t"
            "s_load_dwordx8 %3, %8, 0x60\n\t"
            "s_load_dwordx8 %4, %8, 0x80\n\t"
            "s_load_dwordx8 %5, %8, 0xa0\n\t"
            "s_load_dwordx8 %6, %8, 0xc0\n\t"
            "s_load_dwordx8 %7, %8, 0xe0\n\t"
            "s_waitcnt lgkmcnt(0)"
            : "=s"(w0), "=s"(w1), "=s"(w2), "=s"(w3),
              "=s"(w4), "=s"(w5), "=s"(w6), "=s"(w7)
            : "s"(p)
            : "memory");
        FMA8(rf0, w0, 0) FMA8(rf0, w1, 8)
        FMA8(rf1, w2, 0) FMA8(rf1, w3, 8)
        FMA8(rf2, w4, 0) FMA8(rf2, w5, 8)
        FMA8(rf3, w6, 0) FMA8(rf3, w7, 8)
    }
}

__device__ __forceinline__ void cellu(const float* a, float* c, float* h)
{
    float iv = sigmf(a[0]);
    float fv = sigmf(a[1]);
    float gv = tanhf_(a[2]);
    float ov = sigmf(a[3]);
    float c2 = fv * (*c) + iv * gv;
    *c = c2;
    *h = ov * tanhf_(c2);
}

// ---------------- per-step kernels (512 thr, 8 waves, lane=row, 64 rows) ----------------

// clause: 220 blocks (110 rowgrps x 2 halves)
__global__ __launch_bounds__(512, 2) void clause_step_k(
    const float* __restrict__ out_cur, const float* __restrict__ outc0,
    float* __restrict__ ch_cur, const float* __restrict__ ch_prev, float* __restrict__ ccg,
    const int* __restrict__ llits,
    const float* __restrict__ wfcT, const float* __restrict__ cwhhT,
    const float* __restrict__ Bc, int step)
{
    __shared__ float bufT[65 * 64];          // [k][r]
    __shared__ float chT[65 * 64];
    const int tid = threadIdx.x;
    const int lane = tid & 63;
    const int wv = tid >> 6;                 // 0..7 chunk
    const int half = blockIdx.x & 1;
    const int Cb = (blockIdx.x >> 1) * 64;
    const int chunk = __builtin_amdgcn_readfirstlane(wv);
    const int hc = half * 8 + chunk;

    // gather: 8 waves x 8 rows, lane = column k
    for (int i = 0; i < 8; ++i) {
        int srow = wv * 8 + i;
        int c = Cb + srow;
        float v;
        if (step) {
            float ch0 = ch_prev[(size_t)c * 64 + lane];
            chT[lane * 65 + srow] = ch0;
            v = ch0;
        } else {
            v = outc0[(size_t)c * 64 + lane];
        }
        const int* lp = llits + c * KK_;
        float t0 = out_cur[(size_t)lp[0] * 64 + lane];
        float t1 = out_cur[(size_t)lp[1] * 64 + lane];
        float t2 = out_cur[(size_t)lp[2] * 64 + lane];
        float t3 = out_cur[(size_t)lp[3] * 64 + lane];
        float t4 = out_cur[(size_t)lp[4] * 64 + lane];
        float t5 = out_cur[(size_t)lp[5] * 64 + lane];
        float t6 = out_cur[(size_t)lp[6] * 64 + lane];
        float t7 = out_cur[(size_t)lp[7] * 64 + lane];
        float t8 = out_cur[(size_t)lp[8] * 64 + lane];
        float t9 = out_cur[(size_t)lp[9] * 64 + lane];
        float ta = out_cur[(size_t)lp[10] * 64 + lane];
        float tb = out_cur[(size_t)lp[11] * 64 + lane];
        v += t0 + t1 + t2 + t3 + t4 + t5 + t6 + t7 + t8 + t9 + ta + tb;
        bufT[lane * 65 + srow] = v;
    }
    __syncthreads();

    float acc[16];
    if (step) {
#pragma unroll
        for (int i = 0; i < 16; ++i) acc[i] = 0.f;
        gemmS(chT, 0, cwhhT + hc * 1024, acc);       // ch(s-1) @ whh
#pragma unroll
        for (int u4 = 0; u4 < 4; ++u4)
#pragma unroll
            for (int g = 0; g < 4; ++g)
                acc[u4 * 4 + g] += Bc[g * 64 + half * 32 + chunk * 4 + u4];
    } else {
#pragma unroll
        for (int u4 = 0; u4 < 4; ++u4)
#pragma unroll
            for (int g = 0; g < 4; ++g)
                acc[u4 * 4 + g] = Bc[g * 64 + half * 32 + chunk * 4 + u4];
    }
    gemmS(bufT, 0, wfcT + hc * 1024, acc);           // folded l_msg

    // cell
    const size_t rowbase = (size_t)(Cb + lane) * 64 + half * 32 + chunk * 4;
    float cc4[4], h4[4];
    if (step) {
        float4 cp = *(const float4*)(ccg + rowbase);
        cc4[0] = cp.x; cc4[1] = cp.y; cc4[2] = cp.z; cc4[3] = cp.w;
    } else { cc4[0] = cc4[1] = cc4[2] = cc4[3] = 0.f; }
#pragma unroll
    for (int u4 = 0; u4 < 4; ++u4) cellu(acc + u4 * 4, &cc4[u4], &h4[u4]);

    // stage h/c dense (reuse chT for h, bufT for c): [r][u'] stride 33
    __syncthreads();
#pragma unroll
    for (int u4 = 0; u4 < 4; ++u4) {
        chT[lane * 33 + chunk * 4 + u4]  = h4[u4];
        bufT[lane * 33 + chunk * 4 + u4] = cc4[u4];
    }
    __syncthreads();
    {
        int row = tid >> 5, cl = tid & 31;
#pragma unroll
        for (int p = 0; p < 4; ++p) {
            int rr = row + p * 16;
            size_t dst = (size_t)(Cb + rr) * 64 + half * 32 + cl;
            ch_cur[dst] = chT[rr * 33 + cl];
            ccg[dst]    = bufT[rr * 33 + cl];
        }
    }
}

// lit: 400 blocks (200 rowgrps x 2 halves)
__global__ __launch_bounds__(512, 2) void lit_step_k(
    const float* __restrict__ out_cur, float* __restrict__ out_nxt,
    const float* __restrict__ chg, float* __restrict__ lcg,
    const int* __restrict__ rowptr, const int* __restrict__ col, const int* __restrict__ cnt,
    const float* __restrict__ wihT, const float* __restrict__ whhT, const float* __restrict__ wflT,
    const float* __restrict__ bfl, const float* __restrict__ Bl,
    const float* __restrict__ Wv, const float* __restrict__ bv, float* __restrict__ vout,
    int step)
{
    __shared__ float bufT[65 * 64 + 1024];   // [k][r] + vote scratch tail
    const int tid = threadIdx.x;
    const int lane = tid & 63;
    const int wv = tid >> 6;
    const int half = blockIdx.x & 1;
    const int Lb = (blockIdx.x >> 1) * 64;
    const int chunk = __builtin_amdgcn_readfirstlane(wv);
    const int hc = half * 8 + chunk;

    // stage out rows -> bufT (lane = column k)
    for (int i = 0; i < 8; ++i) {
        int srow = wv * 8 + i;
        bufT[lane * 65 + srow] = out_cur[(size_t)(Lb + srow) * 64 + lane];
    }
    __syncthreads();

    const float degf = 1.f + (float)cnt[Lb + lane];
    float acc[16];
#pragma unroll
    for (int u4 = 0; u4 < 4; ++u4)
#pragma unroll
        for (int g = 0; g < 4; ++g) {
            int gc = g * 64 + half * 32 + chunk * 4 + u4;
            acc[u4 * 4 + g] = Bl[gc] + degf * bfl[gc];
        }
    gemmS(bufT, 1, wihT + hc * 1024, acc);           // out[flip] @ wih_top (flip = r^1)
    if (step) gemmS(bufT, 0, whhT + hc * 1024, acc); // lh @ whh
    __syncthreads();   // all gemm reads done before gather overwrites

    // padded CSR gather: 8 waves x 8 rows
    for (int i = 0; i < 8; ++i) {
        int srow = wv * 8 + i;
        int l = Lb + srow;
        int e = rowptr[l], eE = rowptr[l + 1];
        float v = bufT[lane * 65 + srow];
        for (; e < eE; e += 8) {
            float t0 = chg[(size_t)col[e    ] * 64 + lane];
            float t1 = chg[(size_t)col[e + 1] * 64 + lane];
            float t2 = chg[(size_t)col[e + 2] * 64 + lane];
            float t3 = chg[(size_t)col[e + 3] * 64 + lane];
            float t4 = chg[(size_t)col[e + 4] * 64 + lane];
            float t5 = chg[(size_t)col[e + 5] * 64 + lane];
            float t6 = chg[(size_t)col[e + 6] * 64 + lane];
            float t7 = chg[(size_t)col[e + 7] * 64 + lane];
            v += ((t0 + t1) + (t2 + t3)) + ((t4 + t5) + (t6 + t7));
        }
        bufT[lane * 65 + srow] = v;
    }
    __syncthreads();
    gemmS(bufT, 0, wflT + hc * 1024, acc);           // folded c_msg

    // cell
    const size_t rowbase = (size_t)(Lb + lane) * 64 + half * 32 + chunk * 4;
    float lc4[4], h4[4];
    if (step) {
        float4 cp = *(const float4*)(lcg + rowbase);
        lc4[0] = cp.x; lc4[1] = cp.y; lc4[2] = cp.z; lc4[3] = cp.w;
    } else { lc4[0] = lc4[1] = lc4[2] = lc4[3] = 0.f; }
#pragma unroll
    for (int u4 = 0; u4 < 4; ++u4) cellu(acc + u4 * 4, &lc4[u4], &h4[u4]);

    // stage h/c dense: h at [0], c at [64*33], vote partials at tail
    float* hS = bufT;
    float* cS = bufT + 64 * 33;
    __syncthreads();
#pragma unroll
    for (int u4 = 0; u4 < 4; ++u4) {
        hS[lane * 33 + chunk * 4 + u4] = h4[u4];
        cS[lane * 33 + chunk * 4 + u4] = lc4[u4];
    }
    if (step == STEPS_ - 1) {
        float p = 0.f;
#pragma unroll
        for (int u4 = 0; u4 < 4; ++u4)
            p += h4[u4] * Wv[half * 32 + chunk * 4 + u4];
        bufT[64 * 66 + lane * 9 + chunk] = p;
    }
    __syncthreads();
    {
        int row = tid >> 5, cl = tid & 31;
#pragma unroll
        for (int p = 0; p < 4; ++p) {
            int rr = row + p * 16;
            size_t dst = (size_t)(Lb + rr) * 64 + half * 32 + cl;
            out_nxt[dst] = hS[rr * 33 + cl];
            lcg[dst]     = cS[rr * 33 + cl];
        }
    }
    if (step == STEPS_ - 1 && wv == 0) {
        float v = (half == 0) ? bv[0] : 0.f;
#pragma unroll
        for (int q = 0; q < 8; ++q) v += bufT[64 * 66 + lane * 9 + q];
        int R = Lb + lane;
        int b = R / NV2_;
        int pos = R - b * NV2_;
        int pi = (pos >> 1) + (pos & 1) * 400;   // undo pair-interleave
        atomicAdd(vout + b * NPG_ + pi, v);
    }
}

// ---------------- host ----------------

extern "C" void kernel_launch(void* const* d_in, const int* in_sizes, int n_in,
                              void* d_out, int out_size, void* d_ws, size_t ws_size,
                              hipStream_t stream)
{
    (void)in_sizes; (void)n_in; (void)out_size; (void)ws_size;
    const float* x    = (const float*)d_in[0];
    const int*   ei   = (const int*)d_in[2];
    const float* liw  = (const float*)d_in[4];
    const float* lib  = (const float*)d_in[5];
    const float* ciw  = (const float*)d_in[6];
    const float* cib  = (const float*)d_in[7];
    const float* lm1  = (const float*)d_in[8];
    const float* lm1b = (const float*)d_in[9];
    const float* lm2  = (const float*)d_in[10];
    const float* lm2b = (const float*)d_in[11];
    const float* lm3  = (const float*)d_in[12];
    const float* lm3b = (const float*)d_in[13];
    const float* cm1  = (const float*)d_in[14];
    const float* cm1b = (const float*)d_in[15];
    const float* cm2  = (const float*)d_in[16];
    const float* cm2b = (const float*)d_in[17];
    const float* cm3  = (const float*)d_in[18];
    const float* cm3b = (const float*)d_in[19];
    const float* lu_wih = (const float*)d_in[20];
    const float* lu_whh = (const float*)d_in[21];
    const float* lu_bih = (const float*)d_in[22];
    const float* lu_bhh = (const float*)d_in[23];
    const float* cu_wih = (const float*)d_in[24];
    const float* cu_whh = (const float*)d_in[25];
    const float* cu_bih = (const float*)d_in[26];
    const float* cu_bhh = (const float*)d_in[27];
    const float* lv1  = (const float*)d_in[28];
    const float* lv1b = (const float*)d_in[29];
    const float* lv2  = (const float*)d_in[30];
    const float* lv2b = (const float*)d_in[31];
    const float* lv3  = (const float*)d_in[32];
    const float* lv3b = (const float*)d_in[33];

    float* F = (float*)d_ws;
    size_t o = 0;
    auto A = [&](size_t n) { float* p = F + o; o += n; return p; };
    float* outA  = A((size_t)NLIT_ * 64);
    float* outB  = A((size_t)NLIT_ * 64);
    float* outc0 = A((size_t)NCLS_ * 64);
    float* chA   = A((size_t)(NCLS_ + 1) * 64);   // +1 dummy zero row
    float* chB   = A((size_t)(NCLS_ + 1) * 64);
    float* ccg   = A((size_t)NCLS_ * 64);
    float* lcg   = A((size_t)NLIT_ * 64);
    float* Wl    = A(4096);
    float* Wc    = A(4096);
    float* bl    = A(64);
    float* bc    = A(64);
    float* Wv    = A(64);
    float* bv    = A(16);
    float* Wfl   = A(64 * 256);
    float* bfl   = A(256);
    float* Bl    = A(256);
    float* Wfc   = A(64 * 256);
    float* Bc    = A(256);
    float* Tbuf  = A(2 * 4096);
    float* ubuf  = A(2 * 64);
    float* wihT  = A(16384);
    float* whhT  = A(16384);
    float* wflT  = A(16384);
    float* cwhhT = A(16384);
    float* wfcT  = A(16384);
    int* I = (int*)(F + o);
    int* llits  = I; I += NE_;
    int* rowptr = I; I += 12804;
    int* cursor = I; I += NLIT_;
    int* pcol   = I; I += 184320;
    int* cnt    = I; I += NLIT_;

    hipMemsetAsync(cnt, 0, NLIT_ * sizeof(int), stream);
    hipMemsetAsync(chA + (size_t)NCLS_ * 64, 0, 64 * sizeof(float), stream);
    hipMemsetAsync(chB + (size_t)NCLS_ * 64, 0, 64 * sizeof(float), stream);
    hipMemsetAsync(d_out, 0, (size_t)NN_ * sizeof(float), stream);

    collapseT_k<<<128, 64, 0, stream>>>(lm1, lm1b, lm2, lm2b, cm1, cm1b, cm2, cm2b, Tbuf, ubuf);
    collapseW_k<<<128, 64, 0, stream>>>(lm3, lm3b, cm3, cm3b, Tbuf, ubuf, Wl, bl, Wc, bc);
    votecol_k<<<1, 64, 0, stream>>>(lv1, lv1b, lv2, lv2b, lv3, lv3b, Wv, bv);
    fold2_k<<<128, 256, 0, stream>>>(Wl, bl, Wc, bc,
                                     lu_wih, lu_bih, lu_bhh,
                                     cu_wih, cu_bih, cu_bhh,
                                     Wfl, bfl, Bl, Wfc, Bc);
    wtrans2_k<<<16, 1024, 0, stream>>>(lu_wih, wihT);
    wtrans2_k<<<16, 1024, 0, stream>>>(lu_whh, whhT);
    wtrans2_k<<<16, 1024, 0, stream>>>(Wfl, wflT);
    wtrans2_k<<<16, 1024, 0, stream>>>(cu_whh, cwhhT);
    wtrans2_k<<<16, 1024, 0, stream>>>(Wfc, wfcT);
    init_k<<<(NN_ * 64 + 255) / 256, 256, 0, stream>>>(x, liw, lib, ciw, cib, outA, outc0);
    econv_k<<<NE_ / 256, 256, 0, stream>>>(ei, llits, cnt);
    scan_k<<<1, 1024, 0, stream>>>(cnt, rowptr, cursor);
    fill_k<<<NE_ / 256, 256, 0, stream>>>(llits, cursor, pcol);
    pad_k<<<(NLIT_ + 255) / 256, 256, 0, stream>>>(cnt, rowptr, pcol);

    for (int s = 0; s < STEPS_; ++s) {
        const float* oc  = (s & 1) ? outB : outA;
        float*       on  = (s & 1) ? outA : outB;
        float*       chc = (s & 1) ? chA : chB;
        const float* chp = (s & 1) ? chB : chA;
        clause_step_k<<<220, 512, 0, stream>>>(oc, outc0, chc, chp, ccg,
                                               llits, wfcT, cwhhT, Bc, s);
        lit_step_k<<<400, 512, 0, stream>>>(oc, on, chc, lcg, rowptr, pcol, cnt,
                                            wihT, whhT, wflT, bfl, Bl,
                                            Wv, bv, (float*)d_out, s);
    }
}

// Round 14
// 1338.687 us; speedup vs baseline: 1.6077x; 1.0231x over previous
//
#include <hip/hip_runtime.h>
#include <math.h>

// NeuroSAT, MI355X. Round 14: r13 + SMEM/DS overlap in gemmS + setup merge.
//  - r13 (scalar-pipe weights) gave 1910->1369us. Remaining stall: gemmS's
//    per-k4 [s_loads -> ds_reads -> wait-all -> FMA] serializes SMEM+DS
//    latencies. Now: issue s_loads (no wait), issue row ds_reads, ONE
//    lgkmcnt(0) + sched_barrier(0) (rule-18 fence), then FMAs ->
//    stall = max(SMEM,DS) not sum. FMA order unchanged -> absmax 0.01269531.
//  - __launch_bounds__(512,4): VGPR<=128, >=2 blocks/CU, no spill.
//  - Setup: wtrans x5 -> 1 kernel; votecol merged into collapseW. The whole
//    launch (incl. setup) graph-replays every iteration, so fewer setup
//    dispatches = direct savings.

#define NV2_   800
#define NC_    440
#define KK_    12
#define NPG_   1240
#define NLIT_  12800
#define NCLS_  7040
#define NE_    84480
#define NN_    19840
#define STEPS_ 23

typedef __attribute__((ext_vector_type(8))) float fx8;

__device__ __forceinline__ float sigmf(float x) { return 1.0f / (1.0f + __expf(-x)); }
__device__ __forceinline__ float tanhf_(float x) { return 1.0f - 2.0f / (__expf(2.0f * x) + 1.0f); }

// ---------------- setup kernels ----------------

__global__ __launch_bounds__(64) void collapseT_k(
    const float* lm1, const float* lm1b, const float* lm2, const float* lm2b,
    const float* cm1, const float* cm1b, const float* cm2, const float* cm2b,
    float* T, float* ub)
{
    int r = blockIdx.x >> 6, i = blockIdx.x & 63, j = threadIdx.x;
    const float* w1 = r ? cm1 : lm1; const float* b1 = r ? cm1b : lm1b;
    const float* w2 = r ? cm2 : lm2; const float* b2 = r ? cm2b : lm2b;
    float s = 0.f;
    for (int k = 0; k < 64; ++k) s += w1[i * 64 + k] * w2[k * 64 + j];
    T[r * 4096 + i * 64 + j] = s;
    if (i == 0) {
        float s2 = 0.f;
        for (int k = 0; k < 64; ++k) s2 += b1[k] * w2[k * 64 + j];
        ub[r * 64 + j] = s2 + b2[j];
    }
}

// blocks 0..127: W collapse; block 128: vote collapse
__global__ __launch_bounds__(64) void collapseW_k(
    const float* lm3, const float* lm3b, const float* cm3, const float* cm3b,
    const float* T, const float* ub,
    float* Wl, float* bl, float* Wc, float* bc,
    const float* lv1, const float* lv1b, const float* lv2, const float* lv2b,
    const float* lv3, const float* lv3b, float* Wv, float* bv)
{
    int t = threadIdx.x;
    if (blockIdx.x < 128) {
        int r = blockIdx.x >> 6, i = blockIdx.x & 63, j = t;
        const float* w3 = r ? cm3 : lm3; const float* b3 = r ? cm3b : lm3b;
        float* W = r ? Wc : Wl; float* bb = r ? bc : bl;
        float s = 0.f;
        for (int k = 0; k < 64; ++k) s += T[r * 4096 + i * 64 + k] * w3[k * 64 + j];
        W[i * 64 + j] = s;
        if (i == 0) {
            float s2 = 0.f;
            for (int k = 0; k < 64; ++k) s2 += ub[r * 64 + k] * w3[k * 64 + j];
            bb[j] = s2 + b3[j];
        }
    } else {
        __shared__ float t3[64];
        __shared__ float ub2[64];
        float s = 0.f;
        for (int j = 0; j < 64; ++j) s += lv2[t * 64 + j] * lv3[j];
        t3[t] = s;
        float s2 = 0.f;
        for (int k = 0; k < 64; ++k) s2 += lv1b[k] * lv2[k * 64 + t];
        ub2[t] = s2 + lv2b[t];
        __syncthreads();
        float s3 = 0.f;
        for (int k = 0; k < 64; ++k) s3 += lv1[t * 64 + k] * t3[k];
        Wv[t] = s3;
        if (t == 0) {
            float v = 0.f;
            for (int j = 0; j < 64; ++j) v += ub2[j] * lv3[j];
            bv[0] = v + lv3b[0];
        }
    }
}

__global__ __launch_bounds__(256) void fold2_k(
    const float* Wl, const float* bl, const float* Wc, const float* bc,
    const float* lwih, const float* lbih, const float* lbhh,
    const float* cwih, const float* cbih, const float* cbhh,
    float* Wfl, float* bfl, float* Bl, float* Wfc, float* Bc)
{
    int t = blockIdx.x >> 6, i = blockIdx.x & 63, j = threadIdx.x;
    if (t == 0) {
        float s = 0.f;
        for (int m = 0; m < 64; ++m) s += Wc[i * 64 + m] * lwih[(64 + m) * 256 + j];
        Wfl[i * 256 + j] = s;
        if (i == 0) {
            float s2 = 0.f;
            for (int m = 0; m < 64; ++m) s2 += bc[m] * lwih[(64 + m) * 256 + j];
            bfl[j] = s2;
            Bl[j] = lbih[j] + lbhh[j];
        }
    } else {
        float s = 0.f;
        for (int m = 0; m < 64; ++m) s += Wl[i * 64 + m] * cwih[m * 256 + j];
        Wfc[i * 256 + j] = s;
        if (i == 0) {
            float s2 = 0.f;
            for (int m = 0; m < 64; ++m) s2 += bl[m] * cwih[m * 256 + j];
            Bc[j] = cbih[j] + cbhh[j] + 13.f * s2;
        }
    }
}

// 5 matrices x 16 hc: [64][256] -> [hc][k][u4*4+g]
struct WT5 { const float* src[5]; float* dst[5]; };
__global__ __launch_bounds__(1024) void wtransAll_k(WT5 a)
{
    int m = blockIdx.x >> 4;
    int hc = blockIdx.x & 15;
    int half = hc >> 3, chunk = hc & 7;
    int t = threadIdx.x;
    int k = t >> 4, u4 = (t >> 2) & 3, g = t & 3;
    a.dst[m][(hc * 64 + k) * 16 + u4 * 4 + g] =
        a.src[m][k * 256 + g * 64 + half * 32 + chunk * 4 + u4];
}

__global__ __launch_bounds__(256) void init_k(
    const float* x, const float* liw, const float* lib, const float* ciw, const float* cib,
    float* out0, float* outc, float* chA, float* chB)
{
    int t = blockIdx.x * 256 + threadIdx.x;
    if (t < 64) {           // zero the dummy chg rows
        chA[(size_t)NCLS_ * 64 + t] = 0.f;
        chB[(size_t)NCLS_ * 64 + t] = 0.f;
    }
    if (t >= NN_ * 64) return;
    int node = t >> 6, j = t & 63;
    int b = node / NPG_;
    int i = node - b * NPG_;
    float x0 = x[node * 2 + 0], x1 = x[node * 2 + 1];
    if (i < NV2_) {
        int sp = (i < 400) ? 2 * i : 2 * (i - 400) + 1;
        out0[(size_t)(b * NV2_ + sp) * 64 + j] = x0 * liw[j] + x1 * liw[64 + j] + lib[j];
    } else {
        outc[(size_t)(b * NC_ + (i - NV2_)) * 64 + j] = x0 * ciw[j] + x1 * ciw[64 + j] + cib[j];
    }
}

__global__ __launch_bounds__(256) void econv_k(const int* ei, int* llits, int* cnt)
{
    int e = blockIdx.x * 256 + threadIdx.x;
    if (e >= NE_) return;
    int g = ei[e];
    int b = g / NPG_;
    int i = g - b * NPG_;
    int sp = (i < 400) ? 2 * i : 2 * (i - 400) + 1;
    int L = b * NV2_ + sp;
    llits[e] = L;
    atomicAdd(cnt + L, 1);
}

__global__ __launch_bounds__(1024) void scan_k(const int* cnt, int* rowptr, int* cursor)
{
    __shared__ int sums[1024];
    int t = threadIdx.x;
    int i0 = t * 13;
    int i1 = i0 + 13; if (i1 > NLIT_) i1 = NLIT_; if (i0 > NLIT_) i0 = NLIT_;
    int s = 0;
    for (int i = i0; i < i1; ++i) s += (cnt[i] + 7) & ~7;
    sums[t] = s;
    __syncthreads();
    for (int off = 1; off < 1024; off <<= 1) {
        int v = (t >= off) ? sums[t - off] : 0;
        __syncthreads();
        sums[t] += v;
        __syncthreads();
    }
    int run = sums[t] - s;
    for (int i = i0; i < i1; ++i) {
        rowptr[i] = run; cursor[i] = run;
        run += (cnt[i] + 7) & ~7;
    }
    if (t == 1023) rowptr[NLIT_] = sums[1023];
}

__global__ __launch_bounds__(256) void fill_k(const int* llits, int* cursor, int* col)
{
    int e = blockIdx.x * 256 + threadIdx.x;
    if (e >= NE_) return;
    int pos = atomicAdd(cursor + llits[e], 1);
    col[pos] = e / KK_;
}

__global__ __launch_bounds__(256) void pad_k(const int* cnt, const int* rowptr, int* col)
{
    int i = blockIdx.x * 256 + threadIdx.x;
    if (i >= NLIT_) return;
    for (int e = rowptr[i] + cnt[i]; e < rowptr[i + 1]; ++e) col[e] = NCLS_;
}

// ---------------- scalar-weight gemm, SMEM/DS overlapped ----------------

#define FMA8(rv, w, off) \
    acc[(off)+0] = fmaf(rv, (w)[0], acc[(off)+0]); \
    acc[(off)+1] = fmaf(rv, (w)[1], acc[(off)+1]); \
    acc[(off)+2] = fmaf(rv, (w)[2], acc[(off)+2]); \
    acc[(off)+3] = fmaf(rv, (w)[3], acc[(off)+3]); \
    acc[(off)+4] = fmaf(rv, (w)[4], acc[(off)+4]); \
    acc[(off)+5] = fmaf(rv, (w)[5], acc[(off)+5]); \
    acc[(off)+6] = fmaf(rv, (w)[6], acc[(off)+6]); \
    acc[(off)+7] = fmaf(rv, (w)[7], acc[(off)+7]);

__device__ __forceinline__ void gemmS(const float* __restrict__ Ls, int rx,
                                      const float* __restrict__ wb, float* acc)
{
    const int r = (threadIdx.x & 63) ^ rx;
#pragma unroll 1
    for (int k4 = 0; k4 < 16; ++k4) {
        fx8 w0, w1, w2, w3, w4, w5, w6, w7;
        const float* p = wb + k4 * 64;
        // issue SMEM loads (no wait) -- they fly while the DS row reads issue
        asm volatile(
            "s_load_dwordx8 %0, %8, 0x0\n\t"
            "s_load_dwordx8 %1, %8, 0x20\n\t"
            "s_load_dwordx8 %2, %8, 0x40\n\t"
            "s_load_dwordx8 %3, %8, 0x60\n\t"
            "s_load_dwordx8 %4, %8, 0x80\n\t"
            "s_load_dwordx8 %5, %8, 0xa0\n\t"
            "s_load_dwordx8 %6, %8, 0xc0\n\t"
            "s_load_dwordx8 %7, %8, 0xe0"
            : "=s"(w0), "=s"(w1), "=s"(w2), "=s"(w3),
              "=s"(w4), "=s"(w5), "=s"(w6), "=s"(w7)
            : "s"(p));
        float rf0 = Ls[(k4 * 4 + 0) * 65 + r];
        float rf1 = Ls[(k4 * 4 + 1) * 65 + r];
        float rf2 = Ls[(k4 * 4 + 2) * 65 + r];
        float rf3 = Ls[(k4 * 4 + 3) * 65 + r];
        asm volatile("s_waitcnt lgkmcnt(0)" ::: "memory");
        __builtin_amdgcn_sched_barrier(0);   // rule-18 fence: keep FMAs below
        FMA8(rf0, w0, 0) FMA8(rf0, w1, 8)
        FMA8(rf1, w2, 0) FMA8(rf1, w3, 8)
        FMA8(rf2, w4, 0) FMA8(rf2, w5, 8)
        FMA8(rf3, w6, 0) FMA8(rf3, w7, 8)
    }
}

__device__ __forceinline__ void cellu(const float* a, float* c, float* h)
{
    float iv = sigmf(a[0]);
    float fv = sigmf(a[1]);
    float gv = tanhf_(a[2]);
    float ov = sigmf(a[3]);
    float c2 = fv * (*c) + iv * gv;
    *c = c2;
    *h = ov * tanhf_(c2);
}

// ---------------- per-step kernels (512 thr, 8 waves, lane=row, 64 rows) ----------------

// clause: 220 blocks (110 rowgrps x 2 halves)
__global__ __launch_bounds__(512, 4) void clause_step_k(
    const float* __restrict__ out_cur, const float* __restrict__ outc0,
    float* __restrict__ ch_cur, const float* __restrict__ ch_prev, float* __restrict__ ccg,
    const int* __restrict__ llits,
    const float* __restrict__ wfcT, const float* __restrict__ cwhhT,
    const float* __restrict__ Bc, int step)
{
    __shared__ float bufT[65 * 64];          // [k][r]
    __shared__ float chT[65 * 64];
    const int tid = threadIdx.x;
    const int lane = tid & 63;
    const int wv = tid >> 6;                 // 0..7 chunk
    const int half = blockIdx.x & 1;
    const int Cb = (blockIdx.x >> 1) * 64;
    const int chunk = __builtin_amdgcn_readfirstlane(wv);
    const int hc = half * 8 + chunk;

    // gather: 8 waves x 8 rows, lane = column k
    for (int i = 0; i < 8; ++i) {
        int srow = wv * 8 + i;
        int c = Cb + srow;
        float v;
        if (step) {
            float ch0 = ch_prev[(size_t)c * 64 + lane];
            chT[lane * 65 + srow] = ch0;
            v = ch0;
        } else {
            v = outc0[(size_t)c * 64 + lane];
        }
        const int* lp = llits + c * KK_;
        float t0 = out_cur[(size_t)lp[0] * 64 + lane];
        float t1 = out_cur[(size_t)lp[1] * 64 + lane];
        float t2 = out_cur[(size_t)lp[2] * 64 + lane];
        float t3 = out_cur[(size_t)lp[3] * 64 + lane];
        float t4 = out_cur[(size_t)lp[4] * 64 + lane];
        float t5 = out_cur[(size_t)lp[5] * 64 + lane];
        float t6 = out_cur[(size_t)lp[6] * 64 + lane];
        float t7 = out_cur[(size_t)lp[7] * 64 + lane];
        float t8 = out_cur[(size_t)lp[8] * 64 + lane];
        float t9 = out_cur[(size_t)lp[9] * 64 + lane];
        float ta = out_cur[(size_t)lp[10] * 64 + lane];
        float tb = out_cur[(size_t)lp[11] * 64 + lane];
        v += t0 + t1 + t2 + t3 + t4 + t5 + t6 + t7 + t8 + t9 + ta + tb;
        bufT[lane * 65 + srow] = v;
    }
    __syncthreads();

    float acc[16];
    if (step) {
#pragma unroll
        for (int i = 0; i < 16; ++i) acc[i] = 0.f;
        gemmS(chT, 0, cwhhT + hc * 1024, acc);       // ch(s-1) @ whh
#pragma unroll
        for (int u4 = 0; u4 < 4; ++u4)
#pragma unroll
            for (int g = 0; g < 4; ++g)
                acc[u4 * 4 + g] += Bc[g * 64 + half * 32 + chunk * 4 + u4];
    } else {
#pragma unroll
        for (int u4 = 0; u4 < 4; ++u4)
#pragma unroll
            for (int g = 0; g < 4; ++g)
                acc[u4 * 4 + g] = Bc[g * 64 + half * 32 + chunk * 4 + u4];
    }
    gemmS(bufT, 0, wfcT + hc * 1024, acc);           // folded l_msg

    const size_t rowbase = (size_t)(Cb + lane) * 64 + half * 32 + chunk * 4;
    float cc4[4], h4[4];
    if (step) {
        float4 cp = *(const float4*)(ccg + rowbase);
        cc4[0] = cp.x; cc4[1] = cp.y; cc4[2] = cp.z; cc4[3] = cp.w;
    } else { cc4[0] = cc4[1] = cc4[2] = cc4[3] = 0.f; }
#pragma unroll
    for (int u4 = 0; u4 < 4; ++u4) cellu(acc + u4 * 4, &cc4[u4], &h4[u4]);

    __syncthreads();
#pragma unroll
    for (int u4 = 0; u4 < 4; ++u4) {
        chT[lane * 33 + chunk * 4 + u4]  = h4[u4];
        bufT[lane * 33 + chunk * 4 + u4] = cc4[u4];
    }
    __syncthreads();
    {
        int row = tid >> 5, cl = tid & 31;
#pragma unroll
        for (int p = 0; p < 4; ++p) {
            int rr = row + p * 16;
            size_t dst = (size_t)(Cb + rr) * 64 + half * 32 + cl;
            ch_cur[dst] = chT[rr * 33 + cl];
            ccg[dst]    = bufT[rr * 33 + cl];
        }
    }
}

// lit: 400 blocks (200 rowgrps x 2 halves)
__global__ __launch_bounds__(512, 4) void lit_step_k(
    const float* __restrict__ out_cur, float* __restrict__ out_nxt,
    const float* __restrict__ chg, float* __restrict__ lcg,
    const int* __restrict__ rowptr, const int* __restrict__ col, const int* __restrict__ cnt,
    const float* __restrict__ wihT, const float* __restrict__ whhT, const float* __restrict__ wflT,
    const float* __restrict__ bfl, const float* __restrict__ Bl,
    const float* __restrict__ Wv, const float* __restrict__ bv, float* __restrict__ vout,
    int step)
{
    __shared__ float bufT[65 * 64 + 1024];   // [k][r] + vote scratch tail
    const int tid = threadIdx.x;
    const int lane = tid & 63;
    const int wv = tid >> 6;
    const int half = blockIdx.x & 1;
    const int Lb = (blockIdx.x >> 1) * 64;
    const int chunk = __builtin_amdgcn_readfirstlane(wv);
    const int hc = half * 8 + chunk;

    for (int i = 0; i < 8; ++i) {
        int srow = wv * 8 + i;
        bufT[lane * 65 + srow] = out_cur[(size_t)(Lb + srow) * 64 + lane];
    }
    __syncthreads();

    const float degf = 1.f + (float)cnt[Lb + lane];
    float acc[16];
#pragma unroll
    for (int u4 = 0; u4 < 4; ++u4)
#pragma unroll
        for (int g = 0; g < 4; ++g) {
            int gc = g * 64 + half * 32 + chunk * 4 + u4;
            acc[u4 * 4 + g] = Bl[gc] + degf * bfl[gc];
        }
    gemmS(bufT, 1, wihT + hc * 1024, acc);           // out[flip] @ wih_top (flip = r^1)
    if (step) gemmS(bufT, 0, whhT + hc * 1024, acc); // lh @ whh
    __syncthreads();   // all gemm reads done before gather overwrites

    for (int i = 0; i < 8; ++i) {
        int srow = wv * 8 + i;
        int l = Lb + srow;
        int e = rowptr[l], eE = rowptr[l + 1];
        float v = bufT[lane * 65 + srow];
        for (; e < eE; e += 8) {
            float t0 = chg[(size_t)col[e    ] * 64 + lane];
            float t1 = chg[(size_t)col[e + 1] * 64 + lane];
            float t2 = chg[(size_t)col[e + 2] * 64 + lane];
            float t3 = chg[(size_t)col[e + 3] * 64 + lane];
            float t4 = chg[(size_t)col[e + 4] * 64 + lane];
            float t5 = chg[(size_t)col[e + 5] * 64 + lane];
            float t6 = chg[(size_t)col[e + 6] * 64 + lane];
            float t7 = chg[(size_t)col[e + 7] * 64 + lane];
            v += ((t0 + t1) + (t2 + t3)) + ((t4 + t5) + (t6 + t7));
        }
        bufT[lane * 65 + srow] = v;
    }
    __syncthreads();
    gemmS(bufT, 0, wflT + hc * 1024, acc);           // folded c_msg

    const size_t rowbase = (size_t)(Lb + lane) * 64 + half * 32 + chunk * 4;
    float lc4[4], h4[4];
    if (step) {
        float4 cp = *(const float4*)(lcg + rowbase);
        lc4[0] = cp.x; lc4[1] = cp.y; lc4[2] = cp.z; lc4[3] = cp.w;
    } else { lc4[0] = lc4[1] = lc4[2] = lc4[3] = 0.f; }
#pragma unroll
    for (int u4 = 0; u4 < 4; ++u4) cellu(acc + u4 * 4, &lc4[u4], &h4[u4]);

    float* hS = bufT;
    float* cS = bufT + 64 * 33;
    __syncthreads();
#pragma unroll
    for (int u4 = 0; u4 < 4; ++u4) {
        hS[lane * 33 + chunk * 4 + u4] = h4[u4];
        cS[lane * 33 + chunk * 4 + u4] = lc4[u4];
    }
    if (step == STEPS_ - 1) {
        float p = 0.f;
#pragma unroll
        for (int u4 = 0; u4 < 4; ++u4)
            p += h4[u4] * Wv[half * 32 + chunk * 4 + u4];
        bufT[64 * 66 + lane * 9 + chunk] = p;
    }
    __syncthreads();
    {
        int row = tid >> 5, cl = tid & 31;
#pragma unroll
        for (int p = 0; p < 4; ++p) {
            int rr = row + p * 16;
            size_t dst = (size_t)(Lb + rr) * 64 + half * 32 + cl;
            out_nxt[dst] = hS[rr * 33 + cl];
            lcg[dst]     = cS[rr * 33 + cl];
        }
    }
    if (step == STEPS_ - 1 && wv == 0) {
        float v = (half == 0) ? bv[0] : 0.f;
#pragma unroll
        for (int q = 0; q < 8; ++q) v += bufT[64 * 66 + lane * 9 + q];
        int R = Lb + lane;
        int b = R / NV2_;
        int pos = R - b * NV2_;
        int pi = (pos >> 1) + (pos & 1) * 400;   // undo pair-interleave
        atomicAdd(vout + b * NPG_ + pi, v);
    }
}

// ---------------- host ----------------

extern "C" void kernel_launch(void* const* d_in, const int* in_sizes, int n_in,
                              void* d_out, int out_size, void* d_ws, size_t ws_size,
                              hipStream_t stream)
{
    (void)in_sizes; (void)n_in; (void)out_size; (void)ws_size;
    const float* x    = (const float*)d_in[0];
    const int*   ei   = (const int*)d_in[2];
    const float* liw  = (const float*)d_in[4];
    const float* lib  = (const float*)d_in[5];
    const float* ciw  = (const float*)d_in[6];
    const float* cib  = (const float*)d_in[7];
    const float* lm1  = (const float*)d_in[8];
    const float* lm1b = (const float*)d_in[9];
    const float* lm2  = (const float*)d_in[10];
    const float* lm2b = (const float*)d_in[11];
    const float* lm3  = (const float*)d_in[12];
    const float* lm3b = (const float*)d_in[13];
    const float* cm1  = (const float*)d_in[14];
    const float* cm1b = (const float*)d_in[15];
    const float* cm2  = (const float*)d_in[16];
    const float* cm2b = (const float*)d_in[17];
    const float* cm3  = (const float*)d_in[18];
    const float* cm3b = (const float*)d_in[19];
    const float* lu_wih = (const float*)d_in[20];
    const float* lu_whh = (const float*)d_in[21];
    const float* lu_bih = (const float*)d_in[22];
    const float* lu_bhh = (const float*)d_in[23];
    const float* cu_wih = (const float*)d_in[24];
    const float* cu_whh = (const float*)d_in[25];
    const float* cu_bih = (const float*)d_in[26];
    const float* cu_bhh = (const float*)d_in[27];
    const float* lv1  = (const float*)d_in[28];
    const float* lv1b = (const float*)d_in[29];
    const float* lv2  = (const float*)d_in[30];
    const float* lv2b = (const float*)d_in[31];
    const float* lv3  = (const float*)d_in[32];
    const float* lv3b = (const float*)d_in[33];

    float* F = (float*)d_ws;
    size_t o = 0;
    auto A = [&](size_t n) { float* p = F + o; o += n; return p; };
    float* outA  = A((size_t)NLIT_ * 64);
    float* outB  = A((size_t)NLIT_ * 64);
    float* outc0 = A((size_t)NCLS_ * 64);
    float* chA   = A((size_t)(NCLS_ + 1) * 64);
    float* chB   = A((size_t)(NCLS_ + 1) * 64);
    float* ccg   = A((size_t)NCLS_ * 64);
    float* lcg   = A((size_t)NLIT_ * 64);
    float* Wl    = A(4096);
    float* Wc    = A(4096);
    float* bl    = A(64);
    float* bc    = A(64);
    float* Wv    = A(64);
    float* bv    = A(16);
    float* Wfl   = A(64 * 256);
    float* bfl   = A(256);
    float* Bl    = A(256);
    float* Wfc   = A(64 * 256);
    float* Bc    = A(256);
    float* Tbuf  = A(2 * 4096);
    float* ubuf  = A(2 * 64);
    float* wihT  = A(16384);
    float* whhT  = A(16384);
    float* wflT  = A(16384);
    float* cwhhT = A(16384);
    float* wfcT  = A(16384);
    int* I = (int*)(F + o);
    int* llits  = I; I += NE_;
    int* rowptr = I; I += 12804;
    int* cursor = I; I += NLIT_;
    int* pcol   = I; I += 184320;
    int* cnt    = I; I += NLIT_;

    hipMemsetAsync(cnt, 0, NLIT_ * sizeof(int), stream);
    hipMemsetAsync(d_out, 0, (size_t)NN_ * sizeof(float), stream);

    collapseT_k<<<128, 64, 0, stream>>>(lm1, lm1b, lm2, lm2b, cm1, cm1b, cm2, cm2b, Tbuf, ubuf);
    collapseW_k<<<129, 64, 0, stream>>>(lm3, lm3b, cm3, cm3b, Tbuf, ubuf, Wl, bl, Wc, bc,
                                        lv1, lv1b, lv2, lv2b, lv3, lv3b, Wv, bv);
    fold2_k<<<128, 256, 0, stream>>>(Wl, bl, Wc, bc,
                                     lu_wih, lu_bih, lu_bhh,
                                     cu_wih, cu_bih, cu_bhh,
                                     Wfl, bfl, Bl, Wfc, Bc);
    WT5 wt;
    wt.src[0] = lu_wih; wt.dst[0] = wihT;
    wt.src[1] = lu_whh; wt.dst[1] = whhT;
    wt.src[2] = Wfl;    wt.dst[2] = wflT;
    wt.src[3] = cu_whh; wt.dst[3] = cwhhT;
    wt.src[4] = Wfc;    wt.dst[4] = wfcT;
    wtransAll_k<<<80, 1024, 0, stream>>>(wt);
    init_k<<<(NN_ * 64 + 255) / 256, 256, 0, stream>>>(x, liw, lib, ciw, cib,
                                                       outA, outc0, chA, chB);
    econv_k<<<NE_ / 256, 256, 0, stream>>>(ei, llits, cnt);
    scan_k<<<1, 1024, 0, stream>>>(cnt, rowptr, cursor);
    fill_k<<<NE_ / 256, 256, 0, stream>>>(llits, cursor, pcol);
    pad_k<<<(NLIT_ + 255) / 256, 256, 0, stream>>>(cnt, rowptr, pcol);

    for (int s = 0; s < STEPS_; ++s) {
        const float* oc  = (s & 1) ? outB : outA;
        float*       on  = (s & 1) ? outA : outB;
        float*       chc = (s & 1) ? chA : chB;
        const float* chp = (s & 1) ? chB : chA;
        clause_step_k<<<220, 512, 0, stream>>>(oc, outc0, chc, chp, ccg,
                                               llits, wfcT, cwhhT, Bc, s);
        lit_step_k<<<400, 512, 0, stream>>>(oc, on, chc, lcg, rowptr, pcol, cnt,
                                            wihT, whhT, wflT, bfl, Bl,
                                            Wv, bv, (float*)d_out, s);
    }
}